// Round 7
// baseline (755.239 us; speedup 1.0000x reference)
//
#include <hip/hip_runtime.h>

// ICNN_net_1503238553972 — round 7: fully barrier-free, wave-private kernel.
// Each wave owns 16 rows end-to-end. f_hat layers: wave computes ALL 128
// out-channels for its 16 rows, in place in a single H buffer (B-frag ds_reads
// all precede epilogue ds_writes; same-wave LDS ops are in-order). A-frags
// (full W per layer) read from L2/L1-resident g_w16. LDS = 24 KB -> 6
// blocks/CU, 24 waves (75% cap). Zero __syncthreads in the whole kernel.
// V phase identical to round 6 (wave-private MFMA, sf deferred), arenas:
// Z1/Z2 overlay the wave's own H rows, Z3 in a dedicated 2 KB/wave region.

typedef _Float16 v2h __attribute__((ext_vector_type(2)));
typedef _Float16 v4h __attribute__((ext_vector_type(4)));
typedef _Float16 v8h __attribute__((ext_vector_type(8)));
typedef float    v4f __attribute__((ext_vector_type(4)));

#define NPTS 500000
#define NBLK ((NPTS + 63) / 64)   // 7813

// offsets in halves inside g_w16
#define OFF_FW    0               // f2..f5: L*16384, [o*128+k]
#define OFF_V2Z   65536           // [j*64+k]
#define OFF_V3Z   69632
#define OFF_V2ZT  73728           // [k*64+j]
#define OFF_V3ZT  77824
#define OFF_VL1T  81920           // [c*64+j]
#define OFF_V2XT  82048
#define OFF_V3XT  82176
#define OFF_VFZ   82304           // [64]
#define OFF_FFW   82368           // [c*128+k]
#define OFF_F1W   82624           // [oc*2+c]
#define W16_DATA  82880
#define W16_TOTAL (W16_DATA + 2048)   // zero pad: junk A-rows stay in-bounds

__device__ __align__(16) _Float16 g_w16[W16_TOTAL];

#if defined(__has_builtin)
#if __has_builtin(__builtin_amdgcn_fdot2)
#define FDOT2(a,b,c) __builtin_amdgcn_fdot2((a),(b),(c),false)
#endif
#endif
#ifndef FDOT2
__device__ __forceinline__ float fdot2_fb(v2h a, v2h b, float c){
  return fmaf((float)a.x, (float)b.x, fmaf((float)a.y, (float)b.y, c));
}
#define FDOT2(a,b,c) fdot2_fb((a),(b),(c))
#endif

__device__ __forceinline__ float srelu(float x){
  float c = fminf(fmaxf(x, 0.f), 1.f);
  return c * fmaf(-0.5f, c, x);
}
__device__ __forceinline__ float sreluD(float x){
  return fminf(fmaxf(x, 0.f), 1.f);
}
__device__ __forceinline__ float lrelu(float x){
  return fmaxf(x, 0.01f * x);
}
__device__ __forceinline__ float sreluD_from_z(float z){
  return fminf(sqrtf(2.f * z), 1.f);
}

// ---------------- prep: fp32 weights -> f16 layouts (+zero pad) ----------------
__global__ __launch_bounds__(256) void prep_kernel(
  const float* __restrict__ f2w, const float* __restrict__ f3w,
  const float* __restrict__ f4w, const float* __restrict__ f5w,
  const float* __restrict__ V2z, const float* __restrict__ V3z,
  const float* __restrict__ Vl1, const float* __restrict__ V2x,
  const float* __restrict__ V3x, const float* __restrict__ Vfz,
  const float* __restrict__ ffw, const float* __restrict__ f1w)
{
  const int i = blockIdx.x * 256 + threadIdx.x;
  if (i >= W16_TOTAL) return;
  if (i >= W16_DATA){ g_w16[i] = (_Float16)0.f; return; }
  float v;
  if (i < 65536){
    const float* W[4] = {f2w, f3w, f4w, f5w};
    v = W[i >> 14][i & 16383];
  } else if (i < 69632)  v = V2z[i - 65536];
  else if (i < 73728)    v = V3z[i - 69632];
  else if (i < 77824){ int r = i - 73728; v = V2z[(r & 63)*64 + (r >> 6)]; }
  else if (i < 81920){ int r = i - 77824; v = V3z[(r & 63)*64 + (r >> 6)]; }
  else if (i < 82048){ int r = i - 81920; v = Vl1[(r & 63)*2 + (r >> 6)]; }
  else if (i < 82176){ int r = i - 82048; v = V2x[(r & 63)*2 + (r >> 6)]; }
  else if (i < 82304){ int r = i - 82176; v = V3x[(r & 63)*2 + (r >> 6)]; }
  else if (i < 82368)    v = Vfz[i - 82304];
  else if (i < 82624)    v = ffw[i - 82368];
  else                   v = f1w[i - 82624];
  g_w16[i] = (_Float16)v;
}

// ---- f_hat layer, wave-private & in-place: 16 rows, all 128 out-ch ----
// B-frags: 4 ds_read_b128 of own rows (all issued before epilogue writes;
// same-wave LDS is in-order -> in-place safe). A: full W from global.
__device__ __forceinline__ void layer_wp(_Float16* Hrow,   // H + (r0)*128
    const _Float16* __restrict__ Wl, const float* __restrict__ Bp,
    int lm, int q)
{
  v8h B[4];
#pragma unroll
  for (int kt = 0; kt < 4; ++kt)
    B[kt] = *(const v8h*)(Hrow + lm*128 + (((kt*4 + q) ^ lm) << 3));

  v4f acc[8];
#pragma unroll
  for (int mt = 0; mt < 8; ++mt) acc[mt] = (v4f){0.f,0.f,0.f,0.f};

#pragma unroll
  for (int mt = 0; mt < 8; ++mt){
#pragma unroll
    for (int kt = 0; kt < 4; ++kt){
      v8h A = *(const v8h*)(Wl + (mt*16 + lm)*128 + kt*32 + q*8);
      acc[mt] = __builtin_amdgcn_mfma_f32_16x16x32_f16(A, B[kt], acc[mt], 0,0,0);
    }
  }

#pragma unroll
  for (int mt = 0; mt < 8; ++mt){
    const int o0 = mt*16 + q*4;
    const v4f bv = *(const v4f*)(Bp + o0);
    v4h hv;
    hv[0] = (_Float16)lrelu(acc[mt][0] + bv[0]);
    hv[1] = (_Float16)lrelu(acc[mt][1] + bv[1]);
    hv[2] = (_Float16)lrelu(acc[mt][2] + bv[2]);
    hv[3] = (_Float16)lrelu(acc[mt][3] + bv[3]);
    *(v4h*)(Hrow + lm*128 + (((o0 >> 3) ^ lm) << 3) + (o0 & 7)) = hv;
  }
}

// ---------------- V-net fwd layer (wave-private arena, 16 rows) ----------------
__device__ __forceinline__ void vfwd_mfma(const _Float16* zin, _Float16* zout,
    const _Float16* __restrict__ Wz, const _Float16* __restrict__ WxT,
    float d0, float d1, int lm, int q)
{
  v4f acc[4];
#pragma unroll
  for (int mt = 0; mt < 4; ++mt) acc[mt] = (v4f){0.f,0.f,0.f,0.f};
  const int rs = lm & 7;
#pragma unroll
  for (int kt = 0; kt < 2; ++kt){
    v8h B = *(const v8h*)(zin + lm*64 + (((kt*4 + q) ^ rs) << 3));
#pragma unroll
    for (int mt = 0; mt < 4; ++mt){
      v8h A = *(const v8h*)(Wz + (mt*16 + lm)*64 + kt*32 + q*8);
      acc[mt] = __builtin_amdgcn_mfma_f32_16x16x32_f16(A, B, acc[mt], 0,0,0);
    }
  }
#pragma unroll
  for (int mt = 0; mt < 4; ++mt){
    const int o0 = mt*16 + q*4;
    v4h hv;
#pragma unroll
    for (int reg = 0; reg < 4; ++reg){
      const int o = o0 + reg;
      const float v = acc[mt][reg] + (float)WxT[o]*d0 + (float)WxT[64 + o]*d1;
      hv[reg] = (_Float16)srelu(v);
    }
    *(v4h*)(zout + lm*64 + (((o0 >> 3) ^ rs) << 3) + (o0 & 7)) = hv;
  }
}

// ---------------- V-net bwd layer (wave-private arena, in-place) ----------------
__device__ __forceinline__ void vbwd_mfma(const _Float16* gin, _Float16* zio,
    const _Float16* __restrict__ WT, int lm, int q)
{
  v4f acc[4];
#pragma unroll
  for (int mt = 0; mt < 4; ++mt) acc[mt] = (v4f){0.f,0.f,0.f,0.f};
  const int rs = lm & 7;
#pragma unroll
  for (int kt = 0; kt < 2; ++kt){
    v8h B = *(const v8h*)(gin + lm*64 + (((kt*4 + q) ^ rs) << 3));
#pragma unroll
    for (int mt = 0; mt < 4; ++mt){
      v8h A = *(const v8h*)(WT + (mt*16 + lm)*64 + kt*32 + q*8);
      acc[mt] = __builtin_amdgcn_mfma_f32_16x16x32_f16(A, B, acc[mt], 0,0,0);
    }
  }
#pragma unroll
  for (int mt = 0; mt < 4; ++mt){
    const int k0 = mt*16 + q*4;
    _Float16* p = zio + lm*64 + (((k0 >> 3) ^ rs) << 3) + (k0 & 7);
    v4h zv = *(const v4h*)p;
    v4h gv;
#pragma unroll
    for (int reg = 0; reg < 4; ++reg)
      gv[reg] = (_Float16)(acc[mt][reg] * sreluD_from_z((float)zv[reg]));
    *(v4h*)p = gv;
  }
}

// ---------------- main: zero barriers ----------------
__global__ __launch_bounds__(256, 6) void icnn_main(
  const float* __restrict__ X, const float* __restrict__ Xst,
  const float* __restrict__ Vfx,
  const float* __restrict__ f1b, const float* __restrict__ f2b,
  const float* __restrict__ f3b, const float* __restrict__ f4b,
  const float* __restrict__ f5b, const float* __restrict__ ffb,
  float* __restrict__ out)
{
  __shared__ __align__(16) char smem[24576];       // 24 KB -> 6 blocks/CU
  _Float16* const H = (_Float16*)smem;             // [64][128] f16, chunk^lm swz

  const int t  = threadIdx.x;
  const int b  = blockIdx.x;
  const int w  = t >> 6;
  const int l  = t & 63;
  const int lm = l & 15;
  const int q  = l >> 4;
  const int r0 = w * 16;

  _Float16* const Hw = H + r0*128;                 // wave's 16 rows (4 KB)
  _Float16* const Z1 = Hw;                         // [16][64] swz8 (overlay)
  _Float16* const Z2 = Hw + 1024;
  _Float16* const Z3 = (_Float16*)(smem + 16384) + w*1024;  // 2 KB/wave

  // row identity for this lane (replicated across q)
  const int rowi = b*64 + r0 + lm;
  const int rc = rowi < NPTS ? rowi : NPTS-1;
  const float2 xx = *(const float2*)(X   + rc*2);
  const float2 xs = *(const float2*)(Xst + rc*2);

  // ---- P1: layer1 (K=2, dot2), wave-private -> own H rows ----
  {
    v2h xh; xh.x = (_Float16)xx.x; xh.y = (_Float16)xx.y;
#pragma unroll
    for (int c8 = 0; c8 < 4; ++c8){
      const int c = q*4 + c8;                      // 16B chunk (8 ch)
      const v4f b0 = *(const v4f*)(f1b + c*8);
      const v4f b1 = *(const v4f*)(f1b + c*8 + 4);
      v8h hv;
#pragma unroll
      for (int j = 0; j < 8; ++j){
        const v2h wv = *(const v2h*)(g_w16 + OFF_F1W + (c*8 + j)*2);
        const float bb = (j < 4) ? b0[j] : b1[j-4];
        hv[j] = (_Float16)lrelu(FDOT2(xh, wv, bb));
      }
      *(v8h*)(Hw + lm*128 + ((c ^ lm) << 3)) = hv;
    }
  }

  // ---- P2: f2..f5 in place, wave-private ----
  layer_wp(Hw, g_w16 + OFF_FW,         f2b, lm, q);
  layer_wp(Hw, g_w16 + OFF_FW + 16384, f3b, lm, q);
  layer_wp(Hw, g_w16 + OFF_FW + 32768, f4b, lm, q);
  layer_wp(Hw, g_w16 + OFF_FW + 49152, f5b, lm, q);

  // ---- P3: head via MFMA — fh = ffw @ h5 (own rows; reads before Z overlay) ----
  v4f aF = (v4f){0.f,0.f,0.f,0.f};
#pragma unroll
  for (int kt = 0; kt < 4; ++kt){
    v8h A = *(const v8h*)(g_w16 + OFF_FFW + lm*128 + kt*32 + q*8);
    v8h B = *(const v8h*)(Hw + lm*128 + (((kt*4 + q) ^ lm) << 3));
    aF = __builtin_amdgcn_mfma_f32_16x16x32_f16(A, B, aF, 0,0,0);
  }

  const float d0 = xx.x - xs.x, d1 = xx.y - xs.y;
  const float vfx0 = Vfx[0], vfx1 = Vfx[1];
  const int rs = lm & 7;

  // ---- P4: z1 = srelu(Vl1 @ d) (overlays own h5 rows — head already read) ----
  {
    v8h w0a = *(const v8h*)(g_w16 + OFF_VL1T + q*16);
    v8h w0b = *(const v8h*)(g_w16 + OFF_VL1T + q*16 + 8);
    v8h w1a = *(const v8h*)(g_w16 + OFF_VL1T + 64 + q*16);
    v8h w1b = *(const v8h*)(g_w16 + OFF_VL1T + 64 + q*16 + 8);
    v8h za, zb;
#pragma unroll
    for (int j = 0; j < 8; ++j){
      za[j] = (_Float16)srelu(fmaf(d0, (float)w0a[j], d1 * (float)w1a[j]));
      zb[j] = (_Float16)srelu(fmaf(d0, (float)w0b[j], d1 * (float)w1b[j]));
    }
    *(v8h*)(Z1 + lm*64 + (((q*2    ) ^ rs) << 3)) = za;
    *(v8h*)(Z1 + lm*64 + (((q*2 + 1) ^ rs) << 3)) = zb;
  }

  // ---- P5: z2, z3 ----
  vfwd_mfma(Z1, Z2, g_w16 + OFF_V2Z, g_w16 + OFF_V2XT, d0, d1, lm, q);
  vfwd_mfma(Z2, Z3, g_w16 + OFF_V3Z, g_w16 + OFF_V3XT, d0, d1, lm, q);

  // ---- P6: zf head via MFMA (A row 0 = Vfz); af/V/sf in regs ----
  float VVr, sf;
  {
    v4f aS = (v4f){0.f,0.f,0.f,0.f};
#pragma unroll
    for (int kt = 0; kt < 2; ++kt){
      v8h A = *(const v8h*)(g_w16 + OFF_VFZ + lm*64 + kt*32 + q*8);
      v8h B = *(const v8h*)(Z3 + lm*64 + (((kt*4 + q) ^ rs) << 3));
      aS = __builtin_amdgcn_mfma_f32_16x16x32_f16(A, B, aS, 0,0,0);
    }
    const float af = fmaf(vfx0, d0, fmaf(vfx1, d1, aS[0]));
    const float zf = srelu(af);
    VVr = srelu(zf) + 0.01f * fmaf(d0, d0, d1*d1);
    sf  = sreluD(zf) * sreluD(af);
  }

  // ---- P7: u3 = Vfz * srelu'(a3) (sf deferred; in place over Z3) ----
#pragma unroll
  for (int cc = 0; cc < 2; ++cc){
    const int c = q*2 + cc;
    _Float16* p = Z3 + lm*64 + ((c ^ rs) << 3);
    v8h z  = *(const v8h*)p;
    v8h vf = *(const v8h*)(g_w16 + OFF_VFZ + c*8);
    v8h u;
#pragma unroll
    for (int j = 0; j < 8; ++j)
      u[j] = (_Float16)((float)vf[j] * sreluD_from_z((float)z[j]));
    *(v8h*)p = u;
  }

  // ---- P8/P9: backward (in place) ----
  vbwd_mfma(Z3, Z2, g_w16 + OFF_V3ZT, lm, q);
  vbwd_mfma(Z2, Z1, g_w16 + OFF_V2ZT, lm, q);

  // ---- P10: gradV via MFMA (A rows 0/1 = Wx^T); apply sf once ----
  float g0, g1;
  {
    v4f aG = (v4f){0.f,0.f,0.f,0.f};
    const _Float16* Zs[3] = {Z1, Z2, Z3};
    const int       Ws[3] = {OFF_VL1T, OFF_V2XT, OFF_V3XT};
#pragma unroll
    for (int li = 0; li < 3; ++li){
#pragma unroll
      for (int kt = 0; kt < 2; ++kt){
        v8h A = *(const v8h*)(g_w16 + Ws[li] + lm*64 + kt*32 + q*8);
        v8h B = *(const v8h*)(Zs[li] + lm*64 + (((kt*4 + q) ^ rs) << 3));
        aG = __builtin_amdgcn_mfma_f32_16x16x32_f16(A, B, aG, 0,0,0);
      }
    }
    g0 = fmaf(0.02f, d0, sf * (vfx0 + aG[0]));
    g1 = fmaf(0.02f, d1, sf * (vfx1 + aG[1]));
  }

  // ---- P11: epilogue (q==0 lanes have everything in regs) ----
  if (q == 0 && rowi < NPTS){
    const float fh0 = aF[0] + ffb[0];
    const float fh1 = aF[1] + ffb[1];
    const float Vn  = fmaf(g0, g0, g1*g1);
    const float num = fmaf(0.1f, VVr, fmaf(fh0, g0, fh1*g1));
    const float fm  = fmaxf(num, 0.f) / (Vn + 1e-10f);
    float2 o;
    o.x = fmaf(-g0, fm, fh0);
    o.y = fmaf(-g1, fm, fh1);
    *(float2*)(out + rowi*2) = o;
  }
}

extern "C" void kernel_launch(void* const* d_in, const int* in_sizes, int n_in,
                              void* d_out, int out_size, void* d_ws, size_t ws_size,
                              hipStream_t stream)
{
  (void)d_ws; (void)ws_size; (void)n_in; (void)in_sizes; (void)out_size;
  const float* X   = (const float*)d_in[0];
  const float* Xst = (const float*)d_in[1];
  const float* Vl1 = (const float*)d_in[2];
  const float* V2x = (const float*)d_in[3];
  const float* V2z = (const float*)d_in[4];
  const float* V3x = (const float*)d_in[5];
  const float* V3z = (const float*)d_in[6];
  const float* Vfx = (const float*)d_in[7];
  const float* Vfz = (const float*)d_in[8];
  const float* f1w = (const float*)d_in[9];
  const float* f1b = (const float*)d_in[10];
  const float* f2w = (const float*)d_in[11];
  const float* f2b = (const float*)d_in[12];
  const float* f3w = (const float*)d_in[13];
  const float* f3b = (const float*)d_in[14];
  const float* f4w = (const float*)d_in[15];
  const float* f4b = (const float*)d_in[16];
  const float* f5w = (const float*)d_in[17];
  const float* f5b = (const float*)d_in[18];
  const float* ffw = (const float*)d_in[19];
  const float* ffb = (const float*)d_in[20];

  prep_kernel<<<(W16_TOTAL + 255)/256, 256, 0, stream>>>(
      f2w, f3w, f4w, f5w, V2z, V3z, Vl1, V2x, V3x, Vfz, ffw, f1w);
  icnn_main<<<NBLK, 256, 0, stream>>>(
      X, Xst, Vfx, f1b, f2b, f3b, f4b, f5b, ffb, (float*)d_out);
}

// Round 8
// 546.983 us; speedup vs baseline: 1.3807x; 1.3807x over previous
//
#include <hip/hip_runtime.h>

// ICNN_net_1503238553972 — round 8: 128-thread / 32-row blocks.
// 2 waves/block, LDS 12.3 KB -> 13 blocks/CU (26 waves, 81% cap).
// f_hat: wave computes 64 out-ch x 32 rows (acc[4][2]); in-place H with a
// 2-wave barrier between B-frag reads and epilogue writes (9 cheap barriers
// total). A-frags (16 KB/layer/wave) from L1/L2-resident g_w16.
// V phase: wave-private 16 rows (round-6 code), Z1/Z2 overlay own H rows,
// Z3 in 2 KB/wave region; sf deferred; epilogue state in registers.
// 500000 = 15625*32 exact -> no bounds clamps anywhere.

typedef _Float16 v2h __attribute__((ext_vector_type(2)));
typedef _Float16 v4h __attribute__((ext_vector_type(4)));
typedef _Float16 v8h __attribute__((ext_vector_type(8)));
typedef float    v4f __attribute__((ext_vector_type(4)));

#define NPTS 500000
#define NBLK (NPTS/32)            // 15625 exact

// offsets in halves inside g_w16
#define OFF_FW    0               // f2..f5: L*16384, [o*128+k]
#define OFF_V2Z   65536           // [j*64+k]
#define OFF_V3Z   69632
#define OFF_V2ZT  73728           // [k*64+j]
#define OFF_V3ZT  77824
#define OFF_VL1T  81920           // [c*64+j]
#define OFF_V2XT  82048
#define OFF_V3XT  82176
#define OFF_VFZ   82304           // [64]
#define OFF_FFW   82368           // [c*128+k]
#define OFF_F1W   82624           // [oc*2+c]
#define W16_DATA  82880
#define W16_TOTAL (W16_DATA + 2048)   // zero pad: junk A-rows stay in-bounds

__device__ __align__(16) _Float16 g_w16[W16_TOTAL];

#if defined(__has_builtin)
#if __has_builtin(__builtin_amdgcn_fdot2)
#define FDOT2(a,b,c) __builtin_amdgcn_fdot2((a),(b),(c),false)
#endif
#endif
#ifndef FDOT2
__device__ __forceinline__ float fdot2_fb(v2h a, v2h b, float c){
  return fmaf((float)a.x, (float)b.x, fmaf((float)a.y, (float)b.y, c));
}
#define FDOT2(a,b,c) fdot2_fb((a),(b),(c))
#endif

__device__ __forceinline__ float srelu(float x){
  float c = fminf(fmaxf(x, 0.f), 1.f);
  return c * fmaf(-0.5f, c, x);
}
__device__ __forceinline__ float sreluD(float x){
  return fminf(fmaxf(x, 0.f), 1.f);
}
__device__ __forceinline__ float lrelu(float x){
  return fmaxf(x, 0.01f * x);
}
__device__ __forceinline__ float sreluD_from_z(float z){
  return fminf(sqrtf(2.f * z), 1.f);
}

// ---------------- prep: fp32 weights -> f16 layouts (+zero pad) ----------------
__global__ __launch_bounds__(256) void prep_kernel(
  const float* __restrict__ f2w, const float* __restrict__ f3w,
  const float* __restrict__ f4w, const float* __restrict__ f5w,
  const float* __restrict__ V2z, const float* __restrict__ V3z,
  const float* __restrict__ Vl1, const float* __restrict__ V2x,
  const float* __restrict__ V3x, const float* __restrict__ Vfz,
  const float* __restrict__ ffw, const float* __restrict__ f1w)
{
  const int i = blockIdx.x * 256 + threadIdx.x;
  if (i >= W16_TOTAL) return;
  if (i >= W16_DATA){ g_w16[i] = (_Float16)0.f; return; }
  float v;
  if (i < 65536){
    const float* W[4] = {f2w, f3w, f4w, f5w};
    v = W[i >> 14][i & 16383];
  } else if (i < 69632)  v = V2z[i - 65536];
  else if (i < 73728)    v = V3z[i - 69632];
  else if (i < 77824){ int r = i - 73728; v = V2z[(r & 63)*64 + (r >> 6)]; }
  else if (i < 81920){ int r = i - 77824; v = V3z[(r & 63)*64 + (r >> 6)]; }
  else if (i < 82048){ int r = i - 81920; v = Vl1[(r & 63)*2 + (r >> 6)]; }
  else if (i < 82176){ int r = i - 82048; v = V2x[(r & 63)*2 + (r >> 6)]; }
  else if (i < 82304){ int r = i - 82176; v = V3x[(r & 63)*2 + (r >> 6)]; }
  else if (i < 82368)    v = Vfz[i - 82304];
  else if (i < 82624)    v = ffw[i - 82368];
  else                   v = f1w[i - 82624];
  g_w16[i] = (_Float16)v;
}

// ---- f_hat layer: 32 rows, wave = 64 out-ch; in-place H with mid-barrier ----
__device__ __forceinline__ void layer_128(_Float16* H,
    const _Float16* __restrict__ Wl, const float* __restrict__ Bp,
    int w, int lm, int q)
{
  v4f acc[4][2];
#pragma unroll
  for (int mt = 0; mt < 4; ++mt){
    acc[mt][0] = (v4f){0.f,0.f,0.f,0.f};
    acc[mt][1] = (v4f){0.f,0.f,0.f,0.f};
  }
#pragma unroll
  for (int kt = 0; kt < 4; ++kt){
    const int sw = ((kt*4 + q) ^ lm) << 3;
    v8h B0 = *(const v8h*)(H + (     lm)*128 + sw);
    v8h B1 = *(const v8h*)(H + (16 + lm)*128 + sw);
#pragma unroll
    for (int mt = 0; mt < 4; ++mt){
      v8h A = *(const v8h*)(Wl + (w*64 + mt*16 + lm)*128 + kt*32 + q*8);
      acc[mt][0] = __builtin_amdgcn_mfma_f32_16x16x32_f16(A, B0, acc[mt][0], 0,0,0);
      acc[mt][1] = __builtin_amdgcn_mfma_f32_16x16x32_f16(A, B1, acc[mt][1], 0,0,0);
    }
  }
  __syncthreads();   // both waves' B-frag reads complete before any write
#pragma unroll
  for (int mt = 0; mt < 4; ++mt){
    const int o0 = w*64 + mt*16 + q*4;
    const v4f bv = *(const v4f*)(Bp + o0);
    const int coff = (((o0 >> 3) ^ lm) << 3) + (o0 & 7);
#pragma unroll
    for (int nt = 0; nt < 2; ++nt){
      v4h hv;
      hv[0] = (_Float16)lrelu(acc[mt][nt][0] + bv[0]);
      hv[1] = (_Float16)lrelu(acc[mt][nt][1] + bv[1]);
      hv[2] = (_Float16)lrelu(acc[mt][nt][2] + bv[2]);
      hv[3] = (_Float16)lrelu(acc[mt][nt][3] + bv[3]);
      *(v4h*)(H + (nt*16 + lm)*128 + coff) = hv;
    }
  }
  __syncthreads();   // writes visible before next layer's reads
}

// ---------------- V-net fwd layer (wave-private arena, 16 rows) ----------------
__device__ __forceinline__ void vfwd_mfma(const _Float16* zin, _Float16* zout,
    const _Float16* __restrict__ Wz, const _Float16* __restrict__ WxT,
    float d0, float d1, int lm, int q)
{
  v4f acc[4];
#pragma unroll
  for (int mt = 0; mt < 4; ++mt) acc[mt] = (v4f){0.f,0.f,0.f,0.f};
  const int rs = lm & 7;
#pragma unroll
  for (int kt = 0; kt < 2; ++kt){
    v8h B = *(const v8h*)(zin + lm*64 + (((kt*4 + q) ^ rs) << 3));
#pragma unroll
    for (int mt = 0; mt < 4; ++mt){
      v8h A = *(const v8h*)(Wz + (mt*16 + lm)*64 + kt*32 + q*8);
      acc[mt] = __builtin_amdgcn_mfma_f32_16x16x32_f16(A, B, acc[mt], 0,0,0);
    }
  }
#pragma unroll
  for (int mt = 0; mt < 4; ++mt){
    const int o0 = mt*16 + q*4;
    v4h hv;
#pragma unroll
    for (int reg = 0; reg < 4; ++reg){
      const int o = o0 + reg;
      const float v = acc[mt][reg] + (float)WxT[o]*d0 + (float)WxT[64 + o]*d1;
      hv[reg] = (_Float16)srelu(v);
    }
    *(v4h*)(zout + lm*64 + (((o0 >> 3) ^ rs) << 3) + (o0 & 7)) = hv;
  }
}

// ---------------- V-net bwd layer (wave-private arena, in-place) ----------------
__device__ __forceinline__ void vbwd_mfma(const _Float16* gin, _Float16* zio,
    const _Float16* __restrict__ WT, int lm, int q)
{
  v4f acc[4];
#pragma unroll
  for (int mt = 0; mt < 4; ++mt) acc[mt] = (v4f){0.f,0.f,0.f,0.f};
  const int rs = lm & 7;
#pragma unroll
  for (int kt = 0; kt < 2; ++kt){
    v8h B = *(const v8h*)(gin + lm*64 + (((kt*4 + q) ^ rs) << 3));
#pragma unroll
    for (int mt = 0; mt < 4; ++mt){
      v8h A = *(const v8h*)(WT + (mt*16 + lm)*64 + kt*32 + q*8);
      acc[mt] = __builtin_amdgcn_mfma_f32_16x16x32_f16(A, B, acc[mt], 0,0,0);
    }
  }
#pragma unroll
  for (int mt = 0; mt < 4; ++mt){
    const int k0 = mt*16 + q*4;
    _Float16* p = zio + lm*64 + (((k0 >> 3) ^ rs) << 3) + (k0 & 7);
    v4h zv = *(const v4h*)p;
    v4h gv;
#pragma unroll
    for (int reg = 0; reg < 4; ++reg)
      gv[reg] = (_Float16)(acc[mt][reg] * sreluD_from_z((float)zv[reg]));
    *(v4h*)p = gv;
  }
}

// ---------------- main: 128 threads, 32 rows ----------------
__global__ __launch_bounds__(128, 6) void icnn_main(
  const float* __restrict__ X, const float* __restrict__ Xst,
  const float* __restrict__ Vfx,
  const float* __restrict__ f1b, const float* __restrict__ f2b,
  const float* __restrict__ f3b, const float* __restrict__ f4b,
  const float* __restrict__ f5b, const float* __restrict__ ffb,
  float* __restrict__ out)
{
  __shared__ __align__(16) char smem[12288];       // 8 KB H + 2x2 KB Z3
  _Float16* const H = (_Float16*)smem;             // [32][128] f16, chunk^lm swz

  const int t  = threadIdx.x;
  const int b  = blockIdx.x;
  const int w  = t >> 6;        // wave 0/1
  const int l  = t & 63;
  const int lm = l & 15;
  const int q  = l >> 4;

  _Float16* const Hw = H + w*2048;                 // wave's 16 rows (4 KB)
  _Float16* const Z1 = Hw;                         // [16][64] swz8 (overlay)
  _Float16* const Z2 = Hw + 1024;
  _Float16* const Z3 = (_Float16*)(smem + 8192) + w*1024;   // 2 KB/wave

  // row identity for this lane (replicated across q); exact, no clamps
  const int rowi = b*32 + w*16 + lm;
  const float2 xx = *(const float2*)(X   + rowi*2);
  const float2 xs = *(const float2*)(Xst + rowi*2);

  // ---- P1: layer1 (K=2, dot2), wave-private -> own 16 H rows ----
  {
    v2h xh; xh.x = (_Float16)xx.x; xh.y = (_Float16)xx.y;
#pragma unroll
    for (int c8 = 0; c8 < 4; ++c8){
      const int c = q*4 + c8;                      // 16B chunk (8 ch)
      const v4f b0 = *(const v4f*)(f1b + c*8);
      const v4f b1 = *(const v4f*)(f1b + c*8 + 4);
      v8h hv;
#pragma unroll
      for (int j = 0; j < 8; ++j){
        const v2h wv = *(const v2h*)(g_w16 + OFF_F1W + (c*8 + j)*2);
        const float bb = (j < 4) ? b0[j] : b1[j-4];
        hv[j] = (_Float16)lrelu(FDOT2(xh, wv, bb));
      }
      *(v8h*)(Hw + lm*128 + ((c ^ lm) << 3)) = hv;
    }
  }
  __syncthreads();

  // ---- P2: f2..f5 in place (2-wave barriers inside) ----
  layer_128(H, g_w16 + OFF_FW,         f2b, w, lm, q);
  layer_128(H, g_w16 + OFF_FW + 16384, f3b, w, lm, q);
  layer_128(H, g_w16 + OFF_FW + 32768, f4b, w, lm, q);
  layer_128(H, g_w16 + OFF_FW + 49152, f5b, w, lm, q);

  // ---- P3: head via MFMA — fh = ffw @ h5 (own 16 rows) ----
  v4f aF = (v4f){0.f,0.f,0.f,0.f};
#pragma unroll
  for (int kt = 0; kt < 4; ++kt){
    v8h A = *(const v8h*)(g_w16 + OFF_FFW + lm*128 + kt*32 + q*8);
    v8h B = *(const v8h*)(Hw + lm*128 + (((kt*4 + q) ^ lm) << 3));
    aF = __builtin_amdgcn_mfma_f32_16x16x32_f16(A, B, aF, 0,0,0);
  }

  const float d0 = xx.x - xs.x, d1 = xx.y - xs.y;
  const float vfx0 = Vfx[0], vfx1 = Vfx[1];
  const int rs = lm & 7;

  // ---- P4: z1 = srelu(Vl1 @ d) (overlays own h5 rows — head already read) ----
  {
    v8h w0a = *(const v8h*)(g_w16 + OFF_VL1T + q*16);
    v8h w0b = *(const v8h*)(g_w16 + OFF_VL1T + q*16 + 8);
    v8h w1a = *(const v8h*)(g_w16 + OFF_VL1T + 64 + q*16);
    v8h w1b = *(const v8h*)(g_w16 + OFF_VL1T + 64 + q*16 + 8);
    v8h za, zb;
#pragma unroll
    for (int j = 0; j < 8; ++j){
      za[j] = (_Float16)srelu(fmaf(d0, (float)w0a[j], d1 * (float)w1a[j]));
      zb[j] = (_Float16)srelu(fmaf(d0, (float)w0b[j], d1 * (float)w1b[j]));
    }
    *(v8h*)(Z1 + lm*64 + (((q*2    ) ^ rs) << 3)) = za;
    *(v8h*)(Z1 + lm*64 + (((q*2 + 1) ^ rs) << 3)) = zb;
  }

  // ---- P5: z2, z3 (wave-private MFMA) ----
  vfwd_mfma(Z1, Z2, g_w16 + OFF_V2Z, g_w16 + OFF_V2XT, d0, d1, lm, q);
  vfwd_mfma(Z2, Z3, g_w16 + OFF_V3Z, g_w16 + OFF_V3XT, d0, d1, lm, q);

  // ---- P6: zf head via MFMA (A row 0 = Vfz); af/V/sf in regs ----
  float VVr, sf;
  {
    v4f aS = (v4f){0.f,0.f,0.f,0.f};
#pragma unroll
    for (int kt = 0; kt < 2; ++kt){
      v8h A = *(const v8h*)(g_w16 + OFF_VFZ + lm*64 + kt*32 + q*8);
      v8h B = *(const v8h*)(Z3 + lm*64 + (((kt*4 + q) ^ rs) << 3));
      aS = __builtin_amdgcn_mfma_f32_16x16x32_f16(A, B, aS, 0,0,0);
    }
    const float af = fmaf(vfx0, d0, fmaf(vfx1, d1, aS[0]));
    const float zf = srelu(af);
    VVr = srelu(zf) + 0.01f * fmaf(d0, d0, d1*d1);
    sf  = sreluD(zf) * sreluD(af);
  }

  // ---- P7: u3 = Vfz * srelu'(a3) (sf deferred; in place over Z3) ----
#pragma unroll
  for (int cc = 0; cc < 2; ++cc){
    const int c = q*2 + cc;
    _Float16* p = Z3 + lm*64 + ((c ^ rs) << 3);
    v8h z  = *(const v8h*)p;
    v8h vf = *(const v8h*)(g_w16 + OFF_VFZ + c*8);
    v8h u;
#pragma unroll
    for (int j = 0; j < 8; ++j)
      u[j] = (_Float16)((float)vf[j] * sreluD_from_z((float)z[j]));
    *(v8h*)p = u;
  }

  // ---- P8/P9: backward (in place) ----
  vbwd_mfma(Z3, Z2, g_w16 + OFF_V3ZT, lm, q);
  vbwd_mfma(Z2, Z1, g_w16 + OFF_V2ZT, lm, q);

  // ---- P10: gradV via MFMA (A rows 0/1 = Wx^T); apply sf once ----
  float g0, g1;
  {
    v4f aG = (v4f){0.f,0.f,0.f,0.f};
    const _Float16* Zs[3] = {Z1, Z2, Z3};
    const int       Ws[3] = {OFF_VL1T, OFF_V2XT, OFF_V3XT};
#pragma unroll
    for (int li = 0; li < 3; ++li){
#pragma unroll
      for (int kt = 0; kt < 2; ++kt){
        v8h A = *(const v8h*)(g_w16 + Ws[li] + lm*64 + kt*32 + q*8);
        v8h B = *(const v8h*)(Zs[li] + lm*64 + (((kt*4 + q) ^ rs) << 3));
        aG = __builtin_amdgcn_mfma_f32_16x16x32_f16(A, B, aG, 0,0,0);
      }
    }
    g0 = fmaf(0.02f, d0, sf * (vfx0 + aG[0]));
    g1 = fmaf(0.02f, d1, sf * (vfx1 + aG[1]));
  }

  // ---- P11: epilogue (q==0 lanes have everything in regs) ----
  if (q == 0){
    const float fh0 = aF[0] + ffb[0];
    const float fh1 = aF[1] + ffb[1];
    const float Vn  = fmaf(g0, g0, g1*g1);
    const float num = fmaf(0.1f, VVr, fmaf(fh0, g0, fh1*g1));
    const float fm  = fmaxf(num, 0.f) / (Vn + 1e-10f);
    float2 o;
    o.x = fmaf(-g0, fm, fh0);
    o.y = fmaf(-g1, fm, fh1);
    *(float2*)(out + rowi*2) = o;
  }
}

extern "C" void kernel_launch(void* const* d_in, const int* in_sizes, int n_in,
                              void* d_out, int out_size, void* d_ws, size_t ws_size,
                              hipStream_t stream)
{
  (void)d_ws; (void)ws_size; (void)n_in; (void)in_sizes; (void)out_size;
  const float* X   = (const float*)d_in[0];
  const float* Xst = (const float*)d_in[1];
  const float* Vl1 = (const float*)d_in[2];
  const float* V2x = (const float*)d_in[3];
  const float* V2z = (const float*)d_in[4];
  const float* V3x = (const float*)d_in[5];
  const float* V3z = (const float*)d_in[6];
  const float* Vfx = (const float*)d_in[7];
  const float* Vfz = (const float*)d_in[8];
  const float* f1w = (const float*)d_in[9];
  const float* f1b = (const float*)d_in[10];
  const float* f2w = (const float*)d_in[11];
  const float* f2b = (const float*)d_in[12];
  const float* f3w = (const float*)d_in[13];
  const float* f3b = (const float*)d_in[14];
  const float* f4w = (const float*)d_in[15];
  const float* f4b = (const float*)d_in[16];
  const float* f5w = (const float*)d_in[17];
  const float* f5b = (const float*)d_in[18];
  const float* ffw = (const float*)d_in[19];
  const float* ffb = (const float*)d_in[20];

  prep_kernel<<<(W16_TOTAL + 255)/256, 256, 0, stream>>>(
      f2w, f3w, f4w, f5w, V2z, V3z, Vl1, V2x, V3x, Vfz, ffw, f1w);
  icnn_main<<<NBLK, 128, 0, stream>>>(
      X, Xst, Vfx, f1b, f2b, f3b, f4b, f5b, ffb, (float*)d_out);
}

// Round 9
// 511.239 us; speedup vs baseline: 1.4773x; 1.0699x over previous
//
#include <hip/hip_runtime.h>

// ICNN_net_1503238553972 — round 9: round-8 structure, spill fixed.
// ONLY change vs round 8: __launch_bounds__(128,4) (VGPR cap 128). The
// (128,6)/(256,6) bounds made the allocator spill MFMA accumulators to
// scratch (WRITE_SIZE 174 MB -> HBM), which was the whole regression.
// Structure: 128 thr / 32 rows, LDS 12.3 KB (13 blocks/CU cap), f_hat layers
// in-place in H with 2-wave barriers; V phase wave-private (16 rows/wave).

typedef _Float16 v2h __attribute__((ext_vector_type(2)));
typedef _Float16 v4h __attribute__((ext_vector_type(4)));
typedef _Float16 v8h __attribute__((ext_vector_type(8)));
typedef float    v4f __attribute__((ext_vector_type(4)));

#define NPTS 500000
#define NBLK (NPTS/32)            // 15625 exact

// offsets in halves inside g_w16
#define OFF_FW    0               // f2..f5: L*16384, [o*128+k]
#define OFF_V2Z   65536           // [j*64+k]
#define OFF_V3Z   69632
#define OFF_V2ZT  73728           // [k*64+j]
#define OFF_V3ZT  77824
#define OFF_VL1T  81920           // [c*64+j]
#define OFF_V2XT  82048
#define OFF_V3XT  82176
#define OFF_VFZ   82304           // [64]
#define OFF_FFW   82368           // [c*128+k]
#define OFF_F1W   82624           // [oc*2+c]
#define W16_DATA  82880
#define W16_TOTAL (W16_DATA + 2048)   // zero pad: junk A-rows stay in-bounds

__device__ __align__(16) _Float16 g_w16[W16_TOTAL];

#if defined(__has_builtin)
#if __has_builtin(__builtin_amdgcn_fdot2)
#define FDOT2(a,b,c) __builtin_amdgcn_fdot2((a),(b),(c),false)
#endif
#endif
#ifndef FDOT2
__device__ __forceinline__ float fdot2_fb(v2h a, v2h b, float c){
  return fmaf((float)a.x, (float)b.x, fmaf((float)a.y, (float)b.y, c));
}
#define FDOT2(a,b,c) fdot2_fb((a),(b),(c))
#endif

__device__ __forceinline__ float srelu(float x){
  float c = fminf(fmaxf(x, 0.f), 1.f);
  return c * fmaf(-0.5f, c, x);
}
__device__ __forceinline__ float sreluD(float x){
  return fminf(fmaxf(x, 0.f), 1.f);
}
__device__ __forceinline__ float lrelu(float x){
  return fmaxf(x, 0.01f * x);
}
__device__ __forceinline__ float sreluD_from_z(float z){
  return fminf(sqrtf(2.f * z), 1.f);
}

// ---------------- prep: fp32 weights -> f16 layouts (+zero pad) ----------------
__global__ __launch_bounds__(256) void prep_kernel(
  const float* __restrict__ f2w, const float* __restrict__ f3w,
  const float* __restrict__ f4w, const float* __restrict__ f5w,
  const float* __restrict__ V2z, const float* __restrict__ V3z,
  const float* __restrict__ Vl1, const float* __restrict__ V2x,
  const float* __restrict__ V3x, const float* __restrict__ Vfz,
  const float* __restrict__ ffw, const float* __restrict__ f1w)
{
  const int i = blockIdx.x * 256 + threadIdx.x;
  if (i >= W16_TOTAL) return;
  if (i >= W16_DATA){ g_w16[i] = (_Float16)0.f; return; }
  float v;
  if (i < 65536){
    const float* W[4] = {f2w, f3w, f4w, f5w};
    v = W[i >> 14][i & 16383];
  } else if (i < 69632)  v = V2z[i - 65536];
  else if (i < 73728)    v = V3z[i - 69632];
  else if (i < 77824){ int r = i - 73728; v = V2z[(r & 63)*64 + (r >> 6)]; }
  else if (i < 81920){ int r = i - 77824; v = V3z[(r & 63)*64 + (r >> 6)]; }
  else if (i < 82048){ int r = i - 81920; v = Vl1[(r & 63)*2 + (r >> 6)]; }
  else if (i < 82176){ int r = i - 82048; v = V2x[(r & 63)*2 + (r >> 6)]; }
  else if (i < 82304){ int r = i - 82176; v = V3x[(r & 63)*2 + (r >> 6)]; }
  else if (i < 82368)    v = Vfz[i - 82304];
  else if (i < 82624)    v = ffw[i - 82368];
  else                   v = f1w[i - 82624];
  g_w16[i] = (_Float16)v;
}

// ---- f_hat layer: 32 rows, wave = 64 out-ch; in-place H with mid-barrier ----
__device__ __forceinline__ void layer_128(_Float16* H,
    const _Float16* __restrict__ Wl, const float* __restrict__ Bp,
    int w, int lm, int q)
{
  v4f acc[4][2];
#pragma unroll
  for (int mt = 0; mt < 4; ++mt){
    acc[mt][0] = (v4f){0.f,0.f,0.f,0.f};
    acc[mt][1] = (v4f){0.f,0.f,0.f,0.f};
  }
#pragma unroll
  for (int kt = 0; kt < 4; ++kt){
    const int sw = ((kt*4 + q) ^ lm) << 3;
    v8h B0 = *(const v8h*)(H + (     lm)*128 + sw);
    v8h B1 = *(const v8h*)(H + (16 + lm)*128 + sw);
#pragma unroll
    for (int mt = 0; mt < 4; ++mt){
      v8h A = *(const v8h*)(Wl + (w*64 + mt*16 + lm)*128 + kt*32 + q*8);
      acc[mt][0] = __builtin_amdgcn_mfma_f32_16x16x32_f16(A, B0, acc[mt][0], 0,0,0);
      acc[mt][1] = __builtin_amdgcn_mfma_f32_16x16x32_f16(A, B1, acc[mt][1], 0,0,0);
    }
  }
  __syncthreads();   // both waves' B-frag reads complete before any write
#pragma unroll
  for (int mt = 0; mt < 4; ++mt){
    const int o0 = w*64 + mt*16 + q*4;
    const v4f bv = *(const v4f*)(Bp + o0);
    const int coff = (((o0 >> 3) ^ lm) << 3) + (o0 & 7);
#pragma unroll
    for (int nt = 0; nt < 2; ++nt){
      v4h hv;
      hv[0] = (_Float16)lrelu(acc[mt][nt][0] + bv[0]);
      hv[1] = (_Float16)lrelu(acc[mt][nt][1] + bv[1]);
      hv[2] = (_Float16)lrelu(acc[mt][nt][2] + bv[2]);
      hv[3] = (_Float16)lrelu(acc[mt][nt][3] + bv[3]);
      *(v4h*)(H + (nt*16 + lm)*128 + coff) = hv;
    }
  }
  __syncthreads();   // writes visible before next layer's reads
}

// ---------------- V-net fwd layer (wave-private arena, 16 rows) ----------------
__device__ __forceinline__ void vfwd_mfma(const _Float16* zin, _Float16* zout,
    const _Float16* __restrict__ Wz, const _Float16* __restrict__ WxT,
    float d0, float d1, int lm, int q)
{
  v4f acc[4];
#pragma unroll
  for (int mt = 0; mt < 4; ++mt) acc[mt] = (v4f){0.f,0.f,0.f,0.f};
  const int rs = lm & 7;
#pragma unroll
  for (int kt = 0; kt < 2; ++kt){
    v8h B = *(const v8h*)(zin + lm*64 + (((kt*4 + q) ^ rs) << 3));
#pragma unroll
    for (int mt = 0; mt < 4; ++mt){
      v8h A = *(const v8h*)(Wz + (mt*16 + lm)*64 + kt*32 + q*8);
      acc[mt] = __builtin_amdgcn_mfma_f32_16x16x32_f16(A, B, acc[mt], 0,0,0);
    }
  }
#pragma unroll
  for (int mt = 0; mt < 4; ++mt){
    const int o0 = mt*16 + q*4;
    v4h hv;
#pragma unroll
    for (int reg = 0; reg < 4; ++reg){
      const int o = o0 + reg;
      const float v = acc[mt][reg] + (float)WxT[o]*d0 + (float)WxT[64 + o]*d1;
      hv[reg] = (_Float16)srelu(v);
    }
    *(v4h*)(zout + lm*64 + (((o0 >> 3) ^ rs) << 3) + (o0 & 7)) = hv;
  }
}

// ---------------- V-net bwd layer (wave-private arena, in-place) ----------------
__device__ __forceinline__ void vbwd_mfma(const _Float16* gin, _Float16* zio,
    const _Float16* __restrict__ WT, int lm, int q)
{
  v4f acc[4];
#pragma unroll
  for (int mt = 0; mt < 4; ++mt) acc[mt] = (v4f){0.f,0.f,0.f,0.f};
  const int rs = lm & 7;
#pragma unroll
  for (int kt = 0; kt < 2; ++kt){
    v8h B = *(const v8h*)(gin + lm*64 + (((kt*4 + q) ^ rs) << 3));
#pragma unroll
    for (int mt = 0; mt < 4; ++mt){
      v8h A = *(const v8h*)(WT + (mt*16 + lm)*64 + kt*32 + q*8);
      acc[mt] = __builtin_amdgcn_mfma_f32_16x16x32_f16(A, B, acc[mt], 0,0,0);
    }
  }
#pragma unroll
  for (int mt = 0; mt < 4; ++mt){
    const int k0 = mt*16 + q*4;
    _Float16* p = zio + lm*64 + (((k0 >> 3) ^ rs) << 3) + (k0 & 7);
    v4h zv = *(const v4h*)p;
    v4h gv;
#pragma unroll
    for (int reg = 0; reg < 4; ++reg)
      gv[reg] = (_Float16)(acc[mt][reg] * sreluD_from_z((float)zv[reg]));
    *(v4h*)p = gv;
  }
}

// ---------------- main: 128 threads, 32 rows ----------------
__global__ __launch_bounds__(128, 4) void icnn_main(
  const float* __restrict__ X, const float* __restrict__ Xst,
  const float* __restrict__ Vfx,
  const float* __restrict__ f1b, const float* __restrict__ f2b,
  const float* __restrict__ f3b, const float* __restrict__ f4b,
  const float* __restrict__ f5b, const float* __restrict__ ffb,
  float* __restrict__ out)
{
  __shared__ __align__(16) char smem[12288];       // 8 KB H + 2x2 KB Z3
  _Float16* const H = (_Float16*)smem;             // [32][128] f16, chunk^lm swz

  const int t  = threadIdx.x;
  const int b  = blockIdx.x;
  const int w  = t >> 6;        // wave 0/1
  const int l  = t & 63;
  const int lm = l & 15;
  const int q  = l >> 4;

  _Float16* const Hw = H + w*2048;                 // wave's 16 rows (4 KB)
  _Float16* const Z1 = Hw;                         // [16][64] swz8 (overlay)
  _Float16* const Z2 = Hw + 1024;
  _Float16* const Z3 = (_Float16*)(smem + 8192) + w*1024;   // 2 KB/wave

  // row identity for this lane (replicated across q); exact, no clamps
  const int rowi = b*32 + w*16 + lm;
  const float2 xx = *(const float2*)(X   + rowi*2);
  const float2 xs = *(const float2*)(Xst + rowi*2);

  // ---- P1: layer1 (K=2, dot2), wave-private -> own 16 H rows ----
  {
    v2h xh; xh.x = (_Float16)xx.x; xh.y = (_Float16)xx.y;
#pragma unroll
    for (int c8 = 0; c8 < 4; ++c8){
      const int c = q*4 + c8;                      // 16B chunk (8 ch)
      const v4f b0 = *(const v4f*)(f1b + c*8);
      const v4f b1 = *(const v4f*)(f1b + c*8 + 4);
      v8h hv;
#pragma unroll
      for (int j = 0; j < 8; ++j){
        const v2h wv = *(const v2h*)(g_w16 + OFF_F1W + (c*8 + j)*2);
        const float bb = (j < 4) ? b0[j] : b1[j-4];
        hv[j] = (_Float16)lrelu(FDOT2(xh, wv, bb));
      }
      *(v8h*)(Hw + lm*128 + ((c ^ lm) << 3)) = hv;
    }
  }
  __syncthreads();

  // ---- P2: f2..f5 in place (2-wave barriers inside) ----
  layer_128(H, g_w16 + OFF_FW,         f2b, w, lm, q);
  layer_128(H, g_w16 + OFF_FW + 16384, f3b, w, lm, q);
  layer_128(H, g_w16 + OFF_FW + 32768, f4b, w, lm, q);
  layer_128(H, g_w16 + OFF_FW + 49152, f5b, w, lm, q);

  // ---- P3: head via MFMA — fh = ffw @ h5 (own 16 rows) ----
  v4f aF = (v4f){0.f,0.f,0.f,0.f};
#pragma unroll
  for (int kt = 0; kt < 4; ++kt){
    v8h A = *(const v8h*)(g_w16 + OFF_FFW + lm*128 + kt*32 + q*8);
    v8h B = *(const v8h*)(Hw + lm*128 + (((kt*4 + q) ^ lm) << 3));
    aF = __builtin_amdgcn_mfma_f32_16x16x32_f16(A, B, aF, 0,0,0);
  }

  const float d0 = xx.x - xs.x, d1 = xx.y - xs.y;
  const float vfx0 = Vfx[0], vfx1 = Vfx[1];
  const int rs = lm & 7;

  // ---- P4: z1 = srelu(Vl1 @ d) (overlays own h5 rows — head already read) ----
  {
    v8h w0a = *(const v8h*)(g_w16 + OFF_VL1T + q*16);
    v8h w0b = *(const v8h*)(g_w16 + OFF_VL1T + q*16 + 8);
    v8h w1a = *(const v8h*)(g_w16 + OFF_VL1T + 64 + q*16);
    v8h w1b = *(const v8h*)(g_w16 + OFF_VL1T + 64 + q*16 + 8);
    v8h za, zb;
#pragma unroll
    for (int j = 0; j < 8; ++j){
      za[j] = (_Float16)srelu(fmaf(d0, (float)w0a[j], d1 * (float)w1a[j]));
      zb[j] = (_Float16)srelu(fmaf(d0, (float)w0b[j], d1 * (float)w1b[j]));
    }
    *(v8h*)(Z1 + lm*64 + (((q*2    ) ^ rs) << 3)) = za;
    *(v8h*)(Z1 + lm*64 + (((q*2 + 1) ^ rs) << 3)) = zb;
  }

  // ---- P5: z2, z3 (wave-private MFMA) ----
  vfwd_mfma(Z1, Z2, g_w16 + OFF_V2Z, g_w16 + OFF_V2XT, d0, d1, lm, q);
  vfwd_mfma(Z2, Z3, g_w16 + OFF_V3Z, g_w16 + OFF_V3XT, d0, d1, lm, q);

  // ---- P6: zf head via MFMA (A row 0 = Vfz); af/V/sf in regs ----
  float VVr, sf;
  {
    v4f aS = (v4f){0.f,0.f,0.f,0.f};
#pragma unroll
    for (int kt = 0; kt < 2; ++kt){
      v8h A = *(const v8h*)(g_w16 + OFF_VFZ + lm*64 + kt*32 + q*8);
      v8h B = *(const v8h*)(Z3 + lm*64 + (((kt*4 + q) ^ rs) << 3));
      aS = __builtin_amdgcn_mfma_f32_16x16x32_f16(A, B, aS, 0,0,0);
    }
    const float af = fmaf(vfx0, d0, fmaf(vfx1, d1, aS[0]));
    const float zf = srelu(af);
    VVr = srelu(zf) + 0.01f * fmaf(d0, d0, d1*d1);
    sf  = sreluD(zf) * sreluD(af);
  }

  // ---- P7: u3 = Vfz * srelu'(a3) (sf deferred; in place over Z3) ----
#pragma unroll
  for (int cc = 0; cc < 2; ++cc){
    const int c = q*2 + cc;
    _Float16* p = Z3 + lm*64 + ((c ^ rs) << 3);
    v8h z  = *(const v8h*)p;
    v8h vf = *(const v8h*)(g_w16 + OFF_VFZ + c*8);
    v8h u;
#pragma unroll
    for (int j = 0; j < 8; ++j)
      u[j] = (_Float16)((float)vf[j] * sreluD_from_z((float)z[j]));
    *(v8h*)p = u;
  }

  // ---- P8/P9: backward (in place) ----
  vbwd_mfma(Z3, Z2, g_w16 + OFF_V3ZT, lm, q);
  vbwd_mfma(Z2, Z1, g_w16 + OFF_V2ZT, lm, q);

  // ---- P10: gradV via MFMA (A rows 0/1 = Wx^T); apply sf once ----
  float g0, g1;
  {
    v4f aG = (v4f){0.f,0.f,0.f,0.f};
    const _Float16* Zs[3] = {Z1, Z2, Z3};
    const int       Ws[3] = {OFF_VL1T, OFF_V2XT, OFF_V3XT};
#pragma unroll
    for (int li = 0; li < 3; ++li){
#pragma unroll
      for (int kt = 0; kt < 2; ++kt){
        v8h A = *(const v8h*)(g_w16 + Ws[li] + lm*64 + kt*32 + q*8);
        v8h B = *(const v8h*)(Zs[li] + lm*64 + (((kt*4 + q) ^ rs) << 3));
        aG = __builtin_amdgcn_mfma_f32_16x16x32_f16(A, B, aG, 0,0,0);
      }
    }
    g0 = fmaf(0.02f, d0, sf * (vfx0 + aG[0]));
    g1 = fmaf(0.02f, d1, sf * (vfx1 + aG[1]));
  }

  // ---- P11: epilogue (q==0 lanes have everything in regs) ----
  if (q == 0){
    const float fh0 = aF[0] + ffb[0];
    const float fh1 = aF[1] + ffb[1];
    const float Vn  = fmaf(g0, g0, g1*g1);
    const float num = fmaf(0.1f, VVr, fmaf(fh0, g0, fh1*g1));
    const float fm  = fmaxf(num, 0.f) / (Vn + 1e-10f);
    float2 o;
    o.x = fmaf(-g0, fm, fh0);
    o.y = fmaf(-g1, fm, fh1);
    *(float2*)(out + rowi*2) = o;
  }
}

extern "C" void kernel_launch(void* const* d_in, const int* in_sizes, int n_in,
                              void* d_out, int out_size, void* d_ws, size_t ws_size,
                              hipStream_t stream)
{
  (void)d_ws; (void)ws_size; (void)n_in; (void)in_sizes; (void)out_size;
  const float* X   = (const float*)d_in[0];
  const float* Xst = (const float*)d_in[1];
  const float* Vl1 = (const float*)d_in[2];
  const float* V2x = (const float*)d_in[3];
  const float* V2z = (const float*)d_in[4];
  const float* V3x = (const float*)d_in[5];
  const float* V3z = (const float*)d_in[6];
  const float* Vfx = (const float*)d_in[7];
  const float* Vfz = (const float*)d_in[8];
  const float* f1w = (const float*)d_in[9];
  const float* f1b = (const float*)d_in[10];
  const float* f2w = (const float*)d_in[11];
  const float* f2b = (const float*)d_in[12];
  const float* f3w = (const float*)d_in[13];
  const float* f3b = (const float*)d_in[14];
  const float* f4w = (const float*)d_in[15];
  const float* f4b = (const float*)d_in[16];
  const float* f5w = (const float*)d_in[17];
  const float* f5b = (const float*)d_in[18];
  const float* ffw = (const float*)d_in[19];
  const float* ffb = (const float*)d_in[20];

  prep_kernel<<<(W16_TOTAL + 255)/256, 256, 0, stream>>>(
      f2w, f3w, f4w, f5w, V2z, V3z, Vl1, V2x, V3x, Vfz, ffw, f1w);
  icnn_main<<<NBLK, 128, 0, stream>>>(
      X, Xst, Vfx, f1b, f2b, f3b, f4b, f5b, ffb, (float*)d_out);
}

// Round 10
// 364.522 us; speedup vs baseline: 2.0719x; 1.4025x over previous
//
#include <hip/hip_runtime.h>

// ICNN_net_1503238553972 — round 10: two specialized kernels.
// fhat_kernel: 256 thr / 128 rows, in-place H (32 KB), wave=32 out-ch x 128
//   rows (acc[2][8]) -> 64 MFMA per barrier, half per-row A-traffic vs R6.
//   Writes FH (f_hat, fp32) to static g_fh. launch_bounds(256,4), no spill.
// vnet_kernel: 256 thr, 4 wave-private waves x 16 rows, ZERO barriers,
//   24 KB LDS -> 6 blocks/CU (75% cap). V weights 16.5 KB -> L1-resident.
//   R9's verified V-phase math (MFMA fwd/bwd, sf deferred, reg epilogue).
// prep_kernel: weights -> f16 (g_w16) incl. transposed variants, zero pad.

typedef _Float16 v2h __attribute__((ext_vector_type(2)));
typedef _Float16 v4h __attribute__((ext_vector_type(4)));
typedef _Float16 v8h __attribute__((ext_vector_type(8)));
typedef float    v4f __attribute__((ext_vector_type(4)));

#define NPTS 500000
#define FH_BLK  ((NPTS + 127) / 128)   // 3907
#define VN_BLK  ((NPTS + 63) / 64)     // 7813

// offsets in halves inside g_w16
#define OFF_FW    0               // f2..f5: L*16384, [o*128+k]
#define OFF_V2Z   65536           // [j*64+k]
#define OFF_V3Z   69632
#define OFF_V2ZT  73728           // [k*64+j]
#define OFF_V3ZT  77824
#define OFF_VL1T  81920           // [c*64+j]
#define OFF_V2XT  82048
#define OFF_V3XT  82176
#define OFF_VFZ   82304           // [64]
#define OFF_FFW   82368           // [c*128+k]
#define OFF_F1W   82624           // [oc*2+c]
#define W16_DATA  82880
#define W16_TOTAL (W16_DATA + 2048)   // zero pad: junk A-rows stay in-bounds

__device__ __align__(16) _Float16 g_w16[W16_TOTAL];
__device__ __align__(16) float    g_fh[NPTS * 2];   // f_hat per row (fp32)

#if defined(__has_builtin)
#if __has_builtin(__builtin_amdgcn_fdot2)
#define FDOT2(a,b,c) __builtin_amdgcn_fdot2((a),(b),(c),false)
#endif
#endif
#ifndef FDOT2
__device__ __forceinline__ float fdot2_fb(v2h a, v2h b, float c){
  return fmaf((float)a.x, (float)b.x, fmaf((float)a.y, (float)b.y, c));
}
#define FDOT2(a,b,c) fdot2_fb((a),(b),(c))
#endif

__device__ __forceinline__ float srelu(float x){
  float c = fminf(fmaxf(x, 0.f), 1.f);
  return c * fmaf(-0.5f, c, x);
}
__device__ __forceinline__ float sreluD(float x){
  return fminf(fmaxf(x, 0.f), 1.f);
}
__device__ __forceinline__ float lrelu(float x){
  return fmaxf(x, 0.01f * x);
}
__device__ __forceinline__ float sreluD_from_z(float z){
  return fminf(sqrtf(2.f * z), 1.f);
}
__device__ __forceinline__ float dot8(v8h a, v8h b, float s){
  const v2h* ap = (const v2h*)&a;
  const v2h* bp = (const v2h*)&b;
  s = FDOT2(ap[0], bp[0], s);
  s = FDOT2(ap[1], bp[1], s);
  s = FDOT2(ap[2], bp[2], s);
  s = FDOT2(ap[3], bp[3], s);
  return s;
}

// ---------------- prep: fp32 weights -> f16 layouts (+zero pad) ----------------
__global__ __launch_bounds__(256) void prep_kernel(
  const float* __restrict__ f2w, const float* __restrict__ f3w,
  const float* __restrict__ f4w, const float* __restrict__ f5w,
  const float* __restrict__ V2z, const float* __restrict__ V3z,
  const float* __restrict__ Vl1, const float* __restrict__ V2x,
  const float* __restrict__ V3x, const float* __restrict__ Vfz,
  const float* __restrict__ ffw, const float* __restrict__ f1w)
{
  const int i = blockIdx.x * 256 + threadIdx.x;
  if (i >= W16_TOTAL) return;
  if (i >= W16_DATA){ g_w16[i] = (_Float16)0.f; return; }
  float v;
  if (i < 65536){
    const float* W[4] = {f2w, f3w, f4w, f5w};
    v = W[i >> 14][i & 16383];
  } else if (i < 69632)  v = V2z[i - 65536];
  else if (i < 73728)    v = V3z[i - 69632];
  else if (i < 77824){ int r = i - 73728; v = V2z[(r & 63)*64 + (r >> 6)]; }
  else if (i < 81920){ int r = i - 77824; v = V3z[(r & 63)*64 + (r >> 6)]; }
  else if (i < 82048){ int r = i - 81920; v = Vl1[(r & 63)*2 + (r >> 6)]; }
  else if (i < 82176){ int r = i - 82048; v = V2x[(r & 63)*2 + (r >> 6)]; }
  else if (i < 82304){ int r = i - 82176; v = V3x[(r & 63)*2 + (r >> 6)]; }
  else if (i < 82368)    v = Vfz[i - 82304];
  else if (i < 82624)    v = ffw[i - 82368];
  else                   v = f1w[i - 82624];
  g_w16[i] = (_Float16)v;
}

// ================= f_hat kernel: 256 thr, 128 rows =================
// layer: wave w owns out-ch w*32..w*32+31 for all 128 rows (acc[2][8]).
__device__ __forceinline__ void fh_layer(_Float16* H,
    const _Float16* __restrict__ Wl, const float* __restrict__ Bp,
    int w, int lm, int q)
{
  v4f acc[2][8];
#pragma unroll
  for (int mt = 0; mt < 2; ++mt)
#pragma unroll
    for (int nt = 0; nt < 8; ++nt) acc[mt][nt] = (v4f){0.f,0.f,0.f,0.f};

#pragma unroll
  for (int kt = 0; kt < 4; ++kt){
    const int sw = ((kt*4 + q) ^ lm) << 3;
    v8h A0 = *(const v8h*)(Wl + (w*32      + lm)*128 + kt*32 + q*8);
    v8h A1 = *(const v8h*)(Wl + (w*32 + 16 + lm)*128 + kt*32 + q*8);
#pragma unroll
    for (int nt = 0; nt < 8; ++nt){
      v8h B = *(const v8h*)(H + (nt*16 + lm)*128 + sw);
      acc[0][nt] = __builtin_amdgcn_mfma_f32_16x16x32_f16(A0, B, acc[0][nt], 0,0,0);
      acc[1][nt] = __builtin_amdgcn_mfma_f32_16x16x32_f16(A1, B, acc[1][nt], 0,0,0);
    }
  }
  __syncthreads();   // all waves' B reads complete before any write
#pragma unroll
  for (int mt = 0; mt < 2; ++mt){
    const int o0 = w*32 + mt*16 + q*4;
    const v4f bv = *(const v4f*)(Bp + o0);
    const int coff = (((o0 >> 3) ^ lm) << 3) + (o0 & 7);
#pragma unroll
    for (int nt = 0; nt < 8; ++nt){
      v4h hv;
      hv[0] = (_Float16)lrelu(acc[mt][nt][0] + bv[0]);
      hv[1] = (_Float16)lrelu(acc[mt][nt][1] + bv[1]);
      hv[2] = (_Float16)lrelu(acc[mt][nt][2] + bv[2]);
      hv[3] = (_Float16)lrelu(acc[mt][nt][3] + bv[3]);
      *(v4h*)(H + (nt*16 + lm)*128 + coff) = hv;
    }
  }
  __syncthreads();   // writes visible before next layer's reads
}

__global__ __launch_bounds__(256, 4) void fhat_kernel(
  const float* __restrict__ X,
  const float* __restrict__ f1b, const float* __restrict__ f2b,
  const float* __restrict__ f3b, const float* __restrict__ f4b,
  const float* __restrict__ f5b, const float* __restrict__ ffb)
{
  __shared__ __align__(16) _Float16 H[128*128];    // 32 KB, chunk^(r&15) swz
  const int t  = threadIdx.x;
  const int b  = blockIdx.x;
  const int w  = t >> 6;
  const int l  = t & 63;
  const int lm = l & 15;
  const int q  = l >> 4;

  // ---- layer1 (K=2, dot2): thread = (row r, half hf) ----
  {
    const int r = t >> 1, hf = t & 1, rsw = r & 15;
    int g = b*128 + r; if (g > NPTS-1) g = NPTS-1;
    const float2 xv = *(const float2*)(X + g*2);
    v2h xh; xh.x = (_Float16)xv.x; xh.y = (_Float16)xv.y;
#pragma unroll
    for (int c8 = 0; c8 < 8; ++c8){
      const int c = hf*8 + c8;                     // 16B chunk (8 ch)
      const v4f b0 = *(const v4f*)(f1b + c*8);
      const v4f b1 = *(const v4f*)(f1b + c*8 + 4);
      v8h hv;
#pragma unroll
      for (int j = 0; j < 8; ++j){
        const v2h wv = *(const v2h*)(g_w16 + OFF_F1W + (c*8 + j)*2);
        const float bb = (j < 4) ? b0[j] : b1[j-4];
        hv[j] = (_Float16)lrelu(FDOT2(xh, wv, bb));
      }
      *(v8h*)(H + r*128 + ((c ^ rsw) << 3)) = hv;
    }
  }
  __syncthreads();

  // ---- f2..f5 in place ----
  fh_layer(H, g_w16 + OFF_FW,         f2b, w, lm, q);
  fh_layer(H, g_w16 + OFF_FW + 16384, f3b, w, lm, q);
  fh_layer(H, g_w16 + OFF_FW + 32768, f4b, w, lm, q);
  fh_layer(H, g_w16 + OFF_FW + 49152, f5b, w, lm, q);

  // ---- head: thread = (row r, ch c) ----
  {
    const int r = t >> 1, c = t & 1, rsw = r & 15;
    float s = ffb[c];
    const v8h* wf = (const v8h*)(g_w16 + OFF_FFW + c*128);
#pragma unroll
    for (int ck = 0; ck < 16; ++ck){
      v8h h = *(const v8h*)(H + r*128 + ((ck ^ rsw) << 3));
      s = dot8(h, wf[ck], s);
    }
    const int row = b*128 + r;
    if (row < NPTS) g_fh[row*2 + c] = s;
  }
}

// ================= V kernel: 256 thr, 4 wave-private waves x 16 rows =================
__device__ __forceinline__ void vfwd_mfma(const _Float16* zin, _Float16* zout,
    const _Float16* __restrict__ Wz, const _Float16* __restrict__ WxT,
    float d0, float d1, int lm, int q)
{
  v4f acc[4];
#pragma unroll
  for (int mt = 0; mt < 4; ++mt) acc[mt] = (v4f){0.f,0.f,0.f,0.f};
  const int rs = lm & 7;
#pragma unroll
  for (int kt = 0; kt < 2; ++kt){
    v8h B = *(const v8h*)(zin + lm*64 + (((kt*4 + q) ^ rs) << 3));
#pragma unroll
    for (int mt = 0; mt < 4; ++mt){
      v8h A = *(const v8h*)(Wz + (mt*16 + lm)*64 + kt*32 + q*8);
      acc[mt] = __builtin_amdgcn_mfma_f32_16x16x32_f16(A, B, acc[mt], 0,0,0);
    }
  }
#pragma unroll
  for (int mt = 0; mt < 4; ++mt){
    const int o0 = mt*16 + q*4;
    v4h hv;
#pragma unroll
    for (int reg = 0; reg < 4; ++reg){
      const int o = o0 + reg;
      const float v = acc[mt][reg] + (float)WxT[o]*d0 + (float)WxT[64 + o]*d1;
      hv[reg] = (_Float16)srelu(v);
    }
    *(v4h*)(zout + lm*64 + (((o0 >> 3) ^ rs) << 3) + (o0 & 7)) = hv;
  }
}

__device__ __forceinline__ void vbwd_mfma(const _Float16* gin, _Float16* zio,
    const _Float16* __restrict__ WT, int lm, int q)
{
  v4f acc[4];
#pragma unroll
  for (int mt = 0; mt < 4; ++mt) acc[mt] = (v4f){0.f,0.f,0.f,0.f};
  const int rs = lm & 7;
#pragma unroll
  for (int kt = 0; kt < 2; ++kt){
    v8h B = *(const v8h*)(gin + lm*64 + (((kt*4 + q) ^ rs) << 3));
#pragma unroll
    for (int mt = 0; mt < 4; ++mt){
      v8h A = *(const v8h*)(WT + (mt*16 + lm)*64 + kt*32 + q*8);
      acc[mt] = __builtin_amdgcn_mfma_f32_16x16x32_f16(A, B, acc[mt], 0,0,0);
    }
  }
#pragma unroll
  for (int mt = 0; mt < 4; ++mt){
    const int k0 = mt*16 + q*4;
    _Float16* p = zio + lm*64 + (((k0 >> 3) ^ rs) << 3) + (k0 & 7);
    v4h zv = *(const v4h*)p;
    v4h gv;
#pragma unroll
    for (int reg = 0; reg < 4; ++reg)
      gv[reg] = (_Float16)(acc[mt][reg] * sreluD_from_z((float)zv[reg]));
    *(v4h*)p = gv;
  }
}

__global__ __launch_bounds__(256, 4) void vnet_kernel(
  const float* __restrict__ X, const float* __restrict__ Xst,
  const float* __restrict__ Vfx, float* __restrict__ out)
{
  __shared__ __align__(16) char smem[24576];       // 4 waves x 6 KB
  const int t  = threadIdx.x;
  const int b  = blockIdx.x;
  const int w  = t >> 6;
  const int l  = t & 63;
  const int lm = l & 15;
  const int q  = l >> 4;

  _Float16* const Z1 = (_Float16*)(smem + w*6144);        // [16][64] swz8
  _Float16* const Z2 = Z1 + 1024;
  _Float16* const Z3 = Z1 + 2048;

  const int rowi = b*64 + w*16 + lm;
  const int rc = rowi < NPTS ? rowi : NPTS-1;
  const float2 xx = *(const float2*)(X   + rc*2);
  const float2 xs = *(const float2*)(Xst + rc*2);
  const float d0 = xx.x - xs.x, d1 = xx.y - xs.y;
  const float vfx0 = Vfx[0], vfx1 = Vfx[1];
  const int rs = lm & 7;

  // z1 = srelu(Vl1 @ d)
  {
    v8h w0a = *(const v8h*)(g_w16 + OFF_VL1T + q*16);
    v8h w0b = *(const v8h*)(g_w16 + OFF_VL1T + q*16 + 8);
    v8h w1a = *(const v8h*)(g_w16 + OFF_VL1T + 64 + q*16);
    v8h w1b = *(const v8h*)(g_w16 + OFF_VL1T + 64 + q*16 + 8);
    v8h za, zb;
#pragma unroll
    for (int j = 0; j < 8; ++j){
      za[j] = (_Float16)srelu(fmaf(d0, (float)w0a[j], d1 * (float)w1a[j]));
      zb[j] = (_Float16)srelu(fmaf(d0, (float)w0b[j], d1 * (float)w1b[j]));
    }
    *(v8h*)(Z1 + lm*64 + (((q*2    ) ^ rs) << 3)) = za;
    *(v8h*)(Z1 + lm*64 + (((q*2 + 1) ^ rs) << 3)) = zb;
  }

  // z2, z3
  vfwd_mfma(Z1, Z2, g_w16 + OFF_V2Z, g_w16 + OFF_V2XT, d0, d1, lm, q);
  vfwd_mfma(Z2, Z3, g_w16 + OFF_V3Z, g_w16 + OFF_V3XT, d0, d1, lm, q);

  // zf head via MFMA (A row 0 = Vfz)
  float VVr, sf;
  {
    v4f aS = (v4f){0.f,0.f,0.f,0.f};
#pragma unroll
    for (int kt = 0; kt < 2; ++kt){
      v8h A = *(const v8h*)(g_w16 + OFF_VFZ + lm*64 + kt*32 + q*8);
      v8h B = *(const v8h*)(Z3 + lm*64 + (((kt*4 + q) ^ rs) << 3));
      aS = __builtin_amdgcn_mfma_f32_16x16x32_f16(A, B, aS, 0,0,0);
    }
    const float af = fmaf(vfx0, d0, fmaf(vfx1, d1, aS[0]));
    const float zf = srelu(af);
    VVr = srelu(zf) + 0.01f * fmaf(d0, d0, d1*d1);
    sf  = sreluD(zf) * sreluD(af);
  }

  // u3 = Vfz * srelu'(a3) (sf deferred; in place over Z3)
#pragma unroll
  for (int cc = 0; cc < 2; ++cc){
    const int c = q*2 + cc;
    _Float16* p = Z3 + lm*64 + ((c ^ rs) << 3);
    v8h z  = *(const v8h*)p;
    v8h vf = *(const v8h*)(g_w16 + OFF_VFZ + c*8);
    v8h u;
#pragma unroll
    for (int j = 0; j < 8; ++j)
      u[j] = (_Float16)((float)vf[j] * sreluD_from_z((float)z[j]));
    *(v8h*)p = u;
  }

  // backward (in place)
  vbwd_mfma(Z3, Z2, g_w16 + OFF_V3ZT, lm, q);
  vbwd_mfma(Z2, Z1, g_w16 + OFF_V2ZT, lm, q);

  // gradV via MFMA (A rows 0/1 = Wx^T); apply sf once
  float g0, g1;
  {
    v4f aG = (v4f){0.f,0.f,0.f,0.f};
    const _Float16* Zs[3] = {Z1, Z2, Z3};
    const int       Ws[3] = {OFF_VL1T, OFF_V2XT, OFF_V3XT};
#pragma unroll
    for (int li = 0; li < 3; ++li){
#pragma unroll
      for (int kt = 0; kt < 2; ++kt){
        v8h A = *(const v8h*)(g_w16 + Ws[li] + lm*64 + kt*32 + q*8);
        v8h B = *(const v8h*)(Zs[li] + lm*64 + (((kt*4 + q) ^ rs) << 3));
        aG = __builtin_amdgcn_mfma_f32_16x16x32_f16(A, B, aG, 0,0,0);
      }
    }
    g0 = fmaf(0.02f, d0, sf * (vfx0 + aG[0]));
    g1 = fmaf(0.02f, d1, sf * (vfx1 + aG[1]));
  }

  // epilogue (q==0 lanes; FH from global)
  if (q == 0 && rowi < NPTS){
    const float2 fh = *(const float2*)(g_fh + rowi*2);
    const float Vn  = fmaf(g0, g0, g1*g1);
    const float num = fmaf(0.1f, VVr, fmaf(fh.x, g0, fh.y*g1));
    const float fm  = fmaxf(num, 0.f) / (Vn + 1e-10f);
    float2 o;
    o.x = fmaf(-g0, fm, fh.x);
    o.y = fmaf(-g1, fm, fh.y);
    *(float2*)(out + rowi*2) = o;
  }
}

extern "C" void kernel_launch(void* const* d_in, const int* in_sizes, int n_in,
                              void* d_out, int out_size, void* d_ws, size_t ws_size,
                              hipStream_t stream)
{
  (void)d_ws; (void)ws_size; (void)n_in; (void)in_sizes; (void)out_size;
  const float* X   = (const float*)d_in[0];
  const float* Xst = (const float*)d_in[1];
  const float* Vl1 = (const float*)d_in[2];
  const float* V2x = (const float*)d_in[3];
  const float* V2z = (const float*)d_in[4];
  const float* V3x = (const float*)d_in[5];
  const float* V3z = (const float*)d_in[6];
  const float* Vfx = (const float*)d_in[7];
  const float* Vfz = (const float*)d_in[8];
  const float* f1w = (const float*)d_in[9];
  const float* f1b = (const float*)d_in[10];
  const float* f2w = (const float*)d_in[11];
  const float* f2b = (const float*)d_in[12];
  const float* f3w = (const float*)d_in[13];
  const float* f3b = (const float*)d_in[14];
  const float* f4w = (const float*)d_in[15];
  const float* f4b = (const float*)d_in[16];
  const float* f5w = (const float*)d_in[17];
  const float* f5b = (const float*)d_in[18];
  const float* ffw = (const float*)d_in[19];
  const float* ffb = (const float*)d_in[20];

  prep_kernel<<<(W16_TOTAL + 255)/256, 256, 0, stream>>>(
      f2w, f3w, f4w, f5w, V2z, V3z, Vl1, V2x, V3x, Vfz, ffw, f1w);
  fhat_kernel<<<FH_BLK, 256, 0, stream>>>(
      X, f1b, f2b, f3b, f4b, f5b, ffb);
  vnet_kernel<<<VN_BLK, 256, 0, stream>>>(
      X, Xst, Vfx, (float*)d_out);
}

// Round 11
// 362.730 us; speedup vs baseline: 2.0821x; 1.0049x over previous
//
#include <hip/hip_runtime.h>

// ICNN_net_1503238553972 — round 11: heterogeneous fused kernel.
// R10's fhat (256thr/128rows, in-place 32KB H) and vnet (4 wave-private
// waves x 16 rows, barrier-free) blocks CO-SCHEDULED in one kernel,
// interleaved 1:2 via blockIdx%3 so each CU hosts both types: fhat's
// MFMA/barrier stalls are filled by vnet's VALU work (m114 overlap).
// vnet writes (g0,g1,V) to g_grad; tiny combine kernel does the epilogue.

typedef _Float16 v2h __attribute__((ext_vector_type(2)));
typedef _Float16 v4h __attribute__((ext_vector_type(4)));
typedef _Float16 v8h __attribute__((ext_vector_type(8)));
typedef float    v4f __attribute__((ext_vector_type(4)));

#define NPTS 500000
#define FH_BLK  ((NPTS + 127) / 128)   // 3907
#define VN_BLK  ((NPTS + 63) / 64)     // 7813
#define FUSED_GRID 11721               // 3907 fhat + 7813 vnet (+1 spare)

// offsets in halves inside g_w16
#define OFF_FW    0               // f2..f5: L*16384, [o*128+k]
#define OFF_V2Z   65536           // [j*64+k]
#define OFF_V3Z   69632
#define OFF_V2ZT  73728           // [k*64+j]
#define OFF_V3ZT  77824
#define OFF_VL1T  81920           // [c*64+j]
#define OFF_V2XT  82048
#define OFF_V3XT  82176
#define OFF_VFZ   82304           // [64]
#define OFF_FFW   82368           // [c*128+k]
#define OFF_F1W   82624           // [oc*2+c]
#define W16_DATA  82880
#define W16_TOTAL (W16_DATA + 2048)   // zero pad: junk A-rows stay in-bounds

__device__ __align__(16) _Float16 g_w16[W16_TOTAL];
__device__ __align__(16) float    g_fh[NPTS * 2];   // f_hat per row (fp32)
__device__ __align__(16) float4   g_grad[NPTS];     // (g0, g1, V, pad)

#if defined(__has_builtin)
#if __has_builtin(__builtin_amdgcn_fdot2)
#define FDOT2(a,b,c) __builtin_amdgcn_fdot2((a),(b),(c),false)
#endif
#endif
#ifndef FDOT2
__device__ __forceinline__ float fdot2_fb(v2h a, v2h b, float c){
  return fmaf((float)a.x, (float)b.x, fmaf((float)a.y, (float)b.y, c));
}
#define FDOT2(a,b,c) fdot2_fb((a),(b),(c))
#endif

__device__ __forceinline__ float srelu(float x){
  float c = fminf(fmaxf(x, 0.f), 1.f);
  return c * fmaf(-0.5f, c, x);
}
__device__ __forceinline__ float sreluD(float x){
  return fminf(fmaxf(x, 0.f), 1.f);
}
__device__ __forceinline__ float lrelu(float x){
  return fmaxf(x, 0.01f * x);
}
__device__ __forceinline__ float sreluD_from_z(float z){
  return fminf(sqrtf(2.f * z), 1.f);
}
__device__ __forceinline__ float dot8(v8h a, v8h b, float s){
  const v2h* ap = (const v2h*)&a;
  const v2h* bp = (const v2h*)&b;
  s = FDOT2(ap[0], bp[0], s);
  s = FDOT2(ap[1], bp[1], s);
  s = FDOT2(ap[2], bp[2], s);
  s = FDOT2(ap[3], bp[3], s);
  return s;
}

// ---------------- prep: fp32 weights -> f16 layouts (+zero pad) ----------------
__global__ __launch_bounds__(256) void prep_kernel(
  const float* __restrict__ f2w, const float* __restrict__ f3w,
  const float* __restrict__ f4w, const float* __restrict__ f5w,
  const float* __restrict__ V2z, const float* __restrict__ V3z,
  const float* __restrict__ Vl1, const float* __restrict__ V2x,
  const float* __restrict__ V3x, const float* __restrict__ Vfz,
  const float* __restrict__ ffw, const float* __restrict__ f1w)
{
  const int i = blockIdx.x * 256 + threadIdx.x;
  if (i >= W16_TOTAL) return;
  if (i >= W16_DATA){ g_w16[i] = (_Float16)0.f; return; }
  float v;
  if (i < 65536){
    const float* W[4] = {f2w, f3w, f4w, f5w};
    v = W[i >> 14][i & 16383];
  } else if (i < 69632)  v = V2z[i - 65536];
  else if (i < 73728)    v = V3z[i - 69632];
  else if (i < 77824){ int r = i - 73728; v = V2z[(r & 63)*64 + (r >> 6)]; }
  else if (i < 81920){ int r = i - 77824; v = V3z[(r & 63)*64 + (r >> 6)]; }
  else if (i < 82048){ int r = i - 81920; v = Vl1[(r & 63)*2 + (r >> 6)]; }
  else if (i < 82176){ int r = i - 82048; v = V2x[(r & 63)*2 + (r >> 6)]; }
  else if (i < 82304){ int r = i - 82176; v = V3x[(r & 63)*2 + (r >> 6)]; }
  else if (i < 82368)    v = Vfz[i - 82304];
  else if (i < 82624)    v = ffw[i - 82368];
  else                   v = f1w[i - 82624];
  g_w16[i] = (_Float16)v;
}

// ================= fhat block body: 256 thr, 128 rows =================
__device__ __forceinline__ void fh_layer(_Float16* H,
    const _Float16* __restrict__ Wl, const float* __restrict__ Bp,
    int w, int lm, int q)
{
  v4f acc[2][8];
#pragma unroll
  for (int mt = 0; mt < 2; ++mt)
#pragma unroll
    for (int nt = 0; nt < 8; ++nt) acc[mt][nt] = (v4f){0.f,0.f,0.f,0.f};

#pragma unroll
  for (int kt = 0; kt < 4; ++kt){
    const int sw = ((kt*4 + q) ^ lm) << 3;
    v8h A0 = *(const v8h*)(Wl + (w*32      + lm)*128 + kt*32 + q*8);
    v8h A1 = *(const v8h*)(Wl + (w*32 + 16 + lm)*128 + kt*32 + q*8);
#pragma unroll
    for (int nt = 0; nt < 8; ++nt){
      v8h B = *(const v8h*)(H + (nt*16 + lm)*128 + sw);
      acc[0][nt] = __builtin_amdgcn_mfma_f32_16x16x32_f16(A0, B, acc[0][nt], 0,0,0);
      acc[1][nt] = __builtin_amdgcn_mfma_f32_16x16x32_f16(A1, B, acc[1][nt], 0,0,0);
    }
  }
  __syncthreads();   // all waves' B reads complete before any write
#pragma unroll
  for (int mt = 0; mt < 2; ++mt){
    const int o0 = w*32 + mt*16 + q*4;
    const v4f bv = *(const v4f*)(Bp + o0);
    const int coff = (((o0 >> 3) ^ lm) << 3) + (o0 & 7);
#pragma unroll
    for (int nt = 0; nt < 8; ++nt){
      v4h hv;
      hv[0] = (_Float16)lrelu(acc[mt][nt][0] + bv[0]);
      hv[1] = (_Float16)lrelu(acc[mt][nt][1] + bv[1]);
      hv[2] = (_Float16)lrelu(acc[mt][nt][2] + bv[2]);
      hv[3] = (_Float16)lrelu(acc[mt][nt][3] + bv[3]);
      *(v4h*)(H + (nt*16 + lm)*128 + coff) = hv;
    }
  }
  __syncthreads();   // writes visible before next layer's reads
}

__device__ __forceinline__ void fhat_body(int b, _Float16* H,
  const float* __restrict__ X,
  const float* __restrict__ f1b, const float* __restrict__ f2b,
  const float* __restrict__ f3b, const float* __restrict__ f4b,
  const float* __restrict__ f5b, const float* __restrict__ ffb)
{
  const int t  = threadIdx.x;
  const int w  = t >> 6;
  const int l  = t & 63;
  const int lm = l & 15;
  const int q  = l >> 4;

  // layer1 (K=2, dot2): thread = (row r, half hf)
  {
    const int r = t >> 1, hf = t & 1, rsw = r & 15;
    int g = b*128 + r; if (g > NPTS-1) g = NPTS-1;
    const float2 xv = *(const float2*)(X + g*2);
    v2h xh; xh.x = (_Float16)xv.x; xh.y = (_Float16)xv.y;
#pragma unroll
    for (int c8 = 0; c8 < 8; ++c8){
      const int c = hf*8 + c8;
      const v4f b0 = *(const v4f*)(f1b + c*8);
      const v4f b1 = *(const v4f*)(f1b + c*8 + 4);
      v8h hv;
#pragma unroll
      for (int j = 0; j < 8; ++j){
        const v2h wv = *(const v2h*)(g_w16 + OFF_F1W + (c*8 + j)*2);
        const float bb = (j < 4) ? b0[j] : b1[j-4];
        hv[j] = (_Float16)lrelu(FDOT2(xh, wv, bb));
      }
      *(v8h*)(H + r*128 + ((c ^ rsw) << 3)) = hv;
    }
  }
  __syncthreads();

  fh_layer(H, g_w16 + OFF_FW,         f2b, w, lm, q);
  fh_layer(H, g_w16 + OFF_FW + 16384, f3b, w, lm, q);
  fh_layer(H, g_w16 + OFF_FW + 32768, f4b, w, lm, q);
  fh_layer(H, g_w16 + OFF_FW + 49152, f5b, w, lm, q);

  // head: thread = (row r, ch c)
  {
    const int r = t >> 1, c = t & 1, rsw = r & 15;
    float s = ffb[c];
    const v8h* wf = (const v8h*)(g_w16 + OFF_FFW + c*128);
#pragma unroll
    for (int ck = 0; ck < 16; ++ck){
      v8h h = *(const v8h*)(H + r*128 + ((ck ^ rsw) << 3));
      s = dot8(h, wf[ck], s);
    }
    const int row = b*128 + r;
    if (row < NPTS) g_fh[row*2 + c] = s;
  }
}

// ================= vnet block body: 4 wave-private waves x 16 rows =================
__device__ __forceinline__ void vfwd_mfma(const _Float16* zin, _Float16* zout,
    const _Float16* __restrict__ Wz, const _Float16* __restrict__ WxT,
    float d0, float d1, int lm, int q)
{
  v4f acc[4];
#pragma unroll
  for (int mt = 0; mt < 4; ++mt) acc[mt] = (v4f){0.f,0.f,0.f,0.f};
  const int rs = lm & 7;
#pragma unroll
  for (int kt = 0; kt < 2; ++kt){
    v8h B = *(const v8h*)(zin + lm*64 + (((kt*4 + q) ^ rs) << 3));
#pragma unroll
    for (int mt = 0; mt < 4; ++mt){
      v8h A = *(const v8h*)(Wz + (mt*16 + lm)*64 + kt*32 + q*8);
      acc[mt] = __builtin_amdgcn_mfma_f32_16x16x32_f16(A, B, acc[mt], 0,0,0);
    }
  }
#pragma unroll
  for (int mt = 0; mt < 4; ++mt){
    const int o0 = mt*16 + q*4;
    v4h hv;
#pragma unroll
    for (int reg = 0; reg < 4; ++reg){
      const int o = o0 + reg;
      const float v = acc[mt][reg] + (float)WxT[o]*d0 + (float)WxT[64 + o]*d1;
      hv[reg] = (_Float16)srelu(v);
    }
    *(v4h*)(zout + lm*64 + (((o0 >> 3) ^ rs) << 3) + (o0 & 7)) = hv;
  }
}

__device__ __forceinline__ void vbwd_mfma(const _Float16* gin, _Float16* zio,
    const _Float16* __restrict__ WT, int lm, int q)
{
  v4f acc[4];
#pragma unroll
  for (int mt = 0; mt < 4; ++mt) acc[mt] = (v4f){0.f,0.f,0.f,0.f};
  const int rs = lm & 7;
#pragma unroll
  for (int kt = 0; kt < 2; ++kt){
    v8h B = *(const v8h*)(gin + lm*64 + (((kt*4 + q) ^ rs) << 3));
#pragma unroll
    for (int mt = 0; mt < 4; ++mt){
      v8h A = *(const v8h*)(WT + (mt*16 + lm)*64 + kt*32 + q*8);
      acc[mt] = __builtin_amdgcn_mfma_f32_16x16x32_f16(A, B, acc[mt], 0,0,0);
    }
  }
#pragma unroll
  for (int mt = 0; mt < 4; ++mt){
    const int k0 = mt*16 + q*4;
    _Float16* p = zio + lm*64 + (((k0 >> 3) ^ rs) << 3) + (k0 & 7);
    v4h zv = *(const v4h*)p;
    v4h gv;
#pragma unroll
    for (int reg = 0; reg < 4; ++reg)
      gv[reg] = (_Float16)(acc[mt][reg] * sreluD_from_z((float)zv[reg]));
    *(v4h*)p = gv;
  }
}

__device__ __forceinline__ void vnet_body(int b, char* smem,
  const float* __restrict__ X, const float* __restrict__ Xst,
  const float* __restrict__ Vfx)
{
  const int t  = threadIdx.x;
  const int w  = t >> 6;
  const int l  = t & 63;
  const int lm = l & 15;
  const int q  = l >> 4;

  _Float16* const Z1 = (_Float16*)(smem + w*6144);        // [16][64] swz8
  _Float16* const Z2 = Z1 + 1024;
  _Float16* const Z3 = Z1 + 2048;

  const int rowi = b*64 + w*16 + lm;
  const int rc = rowi < NPTS ? rowi : NPTS-1;
  const float2 xx = *(const float2*)(X   + rc*2);
  const float2 xs = *(const float2*)(Xst + rc*2);
  const float d0 = xx.x - xs.x, d1 = xx.y - xs.y;
  const float vfx0 = Vfx[0], vfx1 = Vfx[1];
  const int rs = lm & 7;

  // z1 = srelu(Vl1 @ d)
  {
    v8h w0a = *(const v8h*)(g_w16 + OFF_VL1T + q*16);
    v8h w0b = *(const v8h*)(g_w16 + OFF_VL1T + q*16 + 8);
    v8h w1a = *(const v8h*)(g_w16 + OFF_VL1T + 64 + q*16);
    v8h w1b = *(const v8h*)(g_w16 + OFF_VL1T + 64 + q*16 + 8);
    v8h za, zb;
#pragma unroll
    for (int j = 0; j < 8; ++j){
      za[j] = (_Float16)srelu(fmaf(d0, (float)w0a[j], d1 * (float)w1a[j]));
      zb[j] = (_Float16)srelu(fmaf(d0, (float)w0b[j], d1 * (float)w1b[j]));
    }
    *(v8h*)(Z1 + lm*64 + (((q*2    ) ^ rs) << 3)) = za;
    *(v8h*)(Z1 + lm*64 + (((q*2 + 1) ^ rs) << 3)) = zb;
  }

  // z2, z3
  vfwd_mfma(Z1, Z2, g_w16 + OFF_V2Z, g_w16 + OFF_V2XT, d0, d1, lm, q);
  vfwd_mfma(Z2, Z3, g_w16 + OFF_V3Z, g_w16 + OFF_V3XT, d0, d1, lm, q);

  // zf head via MFMA (A row 0 = Vfz)
  float VVr, sf;
  {
    v4f aS = (v4f){0.f,0.f,0.f,0.f};
#pragma unroll
    for (int kt = 0; kt < 2; ++kt){
      v8h A = *(const v8h*)(g_w16 + OFF_VFZ + lm*64 + kt*32 + q*8);
      v8h B = *(const v8h*)(Z3 + lm*64 + (((kt*4 + q) ^ rs) << 3));
      aS = __builtin_amdgcn_mfma_f32_16x16x32_f16(A, B, aS, 0,0,0);
    }
    const float af = fmaf(vfx0, d0, fmaf(vfx1, d1, aS[0]));
    const float zf = srelu(af);
    VVr = srelu(zf) + 0.01f * fmaf(d0, d0, d1*d1);
    sf  = sreluD(zf) * sreluD(af);
  }

  // u3 = Vfz * srelu'(a3) (sf deferred; in place over Z3)
#pragma unroll
  for (int cc = 0; cc < 2; ++cc){
    const int c = q*2 + cc;
    _Float16* p = Z3 + lm*64 + ((c ^ rs) << 3);
    v8h z  = *(const v8h*)p;
    v8h vf = *(const v8h*)(g_w16 + OFF_VFZ + c*8);
    v8h u;
#pragma unroll
    for (int j = 0; j < 8; ++j)
      u[j] = (_Float16)((float)vf[j] * sreluD_from_z((float)z[j]));
    *(v8h*)p = u;
  }

  // backward (in place)
  vbwd_mfma(Z3, Z2, g_w16 + OFF_V3ZT, lm, q);
  vbwd_mfma(Z2, Z1, g_w16 + OFF_V2ZT, lm, q);

  // gradV via MFMA (A rows 0/1 = Wx^T); apply sf once
  float g0, g1;
  {
    v4f aG = (v4f){0.f,0.f,0.f,0.f};
    const _Float16* Zs[3] = {Z1, Z2, Z3};
    const int       Ws[3] = {OFF_VL1T, OFF_V2XT, OFF_V3XT};
#pragma unroll
    for (int li = 0; li < 3; ++li){
#pragma unroll
      for (int kt = 0; kt < 2; ++kt){
        v8h A = *(const v8h*)(g_w16 + Ws[li] + lm*64 + kt*32 + q*8);
        v8h B = *(const v8h*)(Zs[li] + lm*64 + (((kt*4 + q) ^ rs) << 3));
        aG = __builtin_amdgcn_mfma_f32_16x16x32_f16(A, B, aG, 0,0,0);
      }
    }
    g0 = fmaf(0.02f, d0, sf * (vfx0 + aG[0]));
    g1 = fmaf(0.02f, d1, sf * (vfx1 + aG[1]));
  }

  // write (g0, g1, V) for the combine kernel (q==0 lanes)
  if (q == 0 && rowi < NPTS)
    g_grad[rowi] = make_float4(g0, g1, VVr, 0.f);
}

// ================= fused heterogeneous kernel =================
__global__ __launch_bounds__(256, 4) void fused_kernel(
  const float* __restrict__ X, const float* __restrict__ Xst,
  const float* __restrict__ Vfx,
  const float* __restrict__ f1b, const float* __restrict__ f2b,
  const float* __restrict__ f3b, const float* __restrict__ f4b,
  const float* __restrict__ f5b, const float* __restrict__ ffb)
{
  __shared__ __align__(16) char smem[32768];
  const int g = blockIdx.x;
  const int sel = g % 3;
  if (sel == 0){
    fhat_body(g/3, (_Float16*)smem, X, f1b, f2b, f3b, f4b, f5b, ffb);
  } else {
    const int b = (g/3)*2 + sel - 1;
    if (b < VN_BLK) vnet_body(b, smem, X, Xst, Vfx);
  }
}

// ================= combine epilogue (memory-bound, ~16 MB) =================
__global__ __launch_bounds__(256) void combine_kernel(float* __restrict__ out)
{
  const int i = blockIdx.x * 256 + threadIdx.x;
  if (i >= NPTS) return;
  const float2 fh = *(const float2*)(g_fh + i*2);
  const float4 gr = g_grad[i];
  const float Vn  = fmaf(gr.x, gr.x, gr.y*gr.y);
  const float num = fmaf(0.1f, gr.z, fmaf(fh.x, gr.x, fh.y*gr.y));
  const float fm  = fmaxf(num, 0.f) / (Vn + 1e-10f);
  float2 o;
  o.x = fmaf(-gr.x, fm, fh.x);
  o.y = fmaf(-gr.y, fm, fh.y);
  *(float2*)(out + i*2) = o;
}

extern "C" void kernel_launch(void* const* d_in, const int* in_sizes, int n_in,
                              void* d_out, int out_size, void* d_ws, size_t ws_size,
                              hipStream_t stream)
{
  (void)d_ws; (void)ws_size; (void)n_in; (void)in_sizes; (void)out_size;
  const float* X   = (const float*)d_in[0];
  const float* Xst = (const float*)d_in[1];
  const float* Vl1 = (const float*)d_in[2];
  const float* V2x = (const float*)d_in[3];
  const float* V2z = (const float*)d_in[4];
  const float* V3x = (const float*)d_in[5];
  const float* V3z = (const float*)d_in[6];
  const float* Vfx = (const float*)d_in[7];
  const float* Vfz = (const float*)d_in[8];
  const float* f1w = (const float*)d_in[9];
  const float* f1b = (const float*)d_in[10];
  const float* f2w = (const float*)d_in[11];
  const float* f2b = (const float*)d_in[12];
  const float* f3w = (const float*)d_in[13];
  const float* f3b = (const float*)d_in[14];
  const float* f4w = (const float*)d_in[15];
  const float* f4b = (const float*)d_in[16];
  const float* f5w = (const float*)d_in[17];
  const float* f5b = (const float*)d_in[18];
  const float* ffw = (const float*)d_in[19];
  const float* ffb = (const float*)d_in[20];

  prep_kernel<<<(W16_TOTAL + 255)/256, 256, 0, stream>>>(
      f2w, f3w, f4w, f5w, V2z, V3z, Vl1, V2x, V3x, Vfz, ffw, f1w);
  fused_kernel<<<FUSED_GRID, 256, 0, stream>>>(
      X, Xst, Vfx, f1b, f2b, f3b, f4b, f5b, ffb);
  combine_kernel<<<(NPTS + 255)/256, 256, 0, stream>>>((float*)d_out);
}